// Round 8
// baseline (347.965 us; speedup 1.0000x reference)
//
#include <hip/hip_runtime.h>
#include <math.h>

#define N_    512
#define L_    64
#define DH    256
#define DX    64
#define Q_    8192
#define NTYP  16
#define NMEM  262144
#define NSEG  32768

// ---------------------------------------------------------------- init
__global__ void k_init(int* __restrict__ em, int* __restrict__ eqcnt) {
    int t = blockIdx.x * blockDim.x + threadIdx.x;
    if (t < N_) em[t] = 0x7fffffff;   // segment_min identity (int32 max)
    if (t == 0) *eqcnt = 0;
}

// ======================= segment-sum via counting sort (no f32 atomics) ====
// old path was TCC-atomic-throughput bound: 16.7M lane-atomics ~= 60us.
__global__ __launch_bounds__(256) void k_hist(const int* __restrict__ grp,
                                              int* __restrict__ counts) {
    int e = blockIdx.x * 256 + threadIdx.x;
    atomicAdd(&counts[grp[e]], 1);
}

// one-block exclusive scan of counts[NSEG] -> offsets (and mutable cursor copy)
__global__ __launch_bounds__(1024) void k_scan(const int* __restrict__ counts,
                                               int* __restrict__ offsets,
                                               int* __restrict__ cursor) {
    __shared__ int ls[1024];
    int t = threadIdx.x;
    int c[32];
    int base = t * 32;
    int s = 0;
#pragma unroll
    for (int i = 0; i < 32; i++) { c[i] = counts[base + i]; s += c[i]; }
    ls[t] = s;
    __syncthreads();
    for (int off = 1; off < 1024; off <<= 1) {   // Hillis-Steele inclusive
        int v = (t >= off) ? ls[t - off] : 0;
        __syncthreads();
        ls[t] += v;
        __syncthreads();
    }
    int excl = (t == 0) ? 0 : ls[t - 1];
#pragma unroll
    for (int i = 0; i < 32; i++) {
        offsets[base + i] = excl;
        cursor[base + i] = excl;
        excl += c[i];
    }
}

// bucket the token ids by group (order within group irrelevant for a sum)
__global__ __launch_bounds__(256) void k_bucket(const int* __restrict__ grp,
                                                const int* __restrict__ mem,
                                                int* __restrict__ cursor,
                                                int* __restrict__ sorted_mem) {
    int e = blockIdx.x * 256 + threadIdx.x;
    int g = grp[e];
    int pos = atomicAdd(&cursor[g], 1);
    sorted_mem[pos] = mem[e];
}

// one wave per group: lane = dim; plain loads + one 256B write (incl. zeros
// for empty groups, so no xsum memset needed)
__global__ __launch_bounds__(256) void k_gsum(const float* __restrict__ tok,
                                              const int* __restrict__ sorted_mem,
                                              const int* __restrict__ offsets,
                                              const int* __restrict__ counts,
                                              float* __restrict__ xsum) {
    int g = blockIdx.x * 4 + (threadIdx.x >> 6);
    int lane = threadIdx.x & 63;
    int beg = offsets[g], cnt = counts[g];
    float acc = 0.f;
    for (int j = 0; j < cnt; j++) {
        int m = sorted_mem[beg + j];              // wave-uniform -> scalar
        acc += tok[(size_t)m * 64 + lane];        // coalesced 256B gather
    }
    xsum[(size_t)g * 64 + lane] = acc;
}

// ---------------------------------- fallback: atomic scatter (small ws only)
__global__ __launch_bounds__(256) void k_scatter(const float* __restrict__ tok,
                                                 const int* __restrict__ mem,
                                                 const int* __restrict__ grp,
                                                 float* __restrict__ xsum) {
    long tid = (long)blockIdx.x * 256 + threadIdx.x;
    int e = (int)(tid >> 6);
    int d = (int)(tid & 63);
    int m = mem[e];
    int g = grp[e];
    atomicAdd(&xsum[(size_t)g * 64 + d], tok[(size_t)m * 64 + d]);
}

// --------------------------- qp = cat(h[idx,src],h[idx,dst]) @ Wq^T + bq
__global__ __launch_bounds__(256) void k_qp2(const float* __restrict__ h,
                                             const float* __restrict__ Wq,
                                             const float* __restrict__ bq,
                                             const int* __restrict__ idx,
                                             const int* __restrict__ src,
                                             const int* __restrict__ dst,
                                             float* __restrict__ qp) {
    __shared__ float aT[32][68];
    __shared__ float wT[32][68];
    int qb = (blockIdx.x >> 2) << 6;
    int db = (blockIdx.x & 3) << 6;
    int t = threadIdx.x;
    int tq = t >> 4, td = t & 15;

    int qq0 = t >> 3, qq1 = (t + 256) >> 3;
    int g0 = qb + qq0, g1 = qb + qq1;
    int r0 = idx[g0], s0 = src[g0], e0 = dst[g0];
    int r1 = idx[g1], s1 = src[g1], e1 = dst[g1];
    int kk4a = (t & 7) << 2;

    float acc[4][4] = {{0.f}};

    for (int c = 0; c < 16; c++) {
        int k0 = c << 5;
        int half = (k0 < 256);
        __syncthreads();
        {
            const float* b0 = h + ((size_t)r0 * 64 + (half ? s0 : e0)) * 256 + (k0 & 255) + kk4a;
            const float* b1 = h + ((size_t)r1 * 64 + (half ? s1 : e1)) * 256 + (k0 & 255) + kk4a;
            float4 v0 = *(const float4*)b0;
            float4 v1 = *(const float4*)b1;
            aT[kk4a + 0][qq0] = v0.x; aT[kk4a + 1][qq0] = v0.y;
            aT[kk4a + 2][qq0] = v0.z; aT[kk4a + 3][qq0] = v0.w;
            aT[kk4a + 0][qq1] = v1.x; aT[kk4a + 1][qq1] = v1.y;
            aT[kk4a + 2][qq1] = v1.z; aT[kk4a + 3][qq1] = v1.w;
        }
        {
            for (int i = t; i < 512; i += 256) {
                int dd = i >> 3, kk4 = (i & 7) << 2;
                float4 v = *(const float4*)(Wq + (size_t)(db + dd) * 512 + k0 + kk4);
                wT[kk4 + 0][dd] = v.x; wT[kk4 + 1][dd] = v.y;
                wT[kk4 + 2][dd] = v.z; wT[kk4 + 3][dd] = v.w;
            }
        }
        __syncthreads();
#pragma unroll 8
        for (int kk = 0; kk < 32; kk++) {
            float4 av = *(const float4*)&aT[kk][tq << 2];
            float4 wv = *(const float4*)&wT[kk][td << 2];
            acc[0][0] = fmaf(av.x, wv.x, acc[0][0]);
            acc[0][1] = fmaf(av.x, wv.y, acc[0][1]);
            acc[0][2] = fmaf(av.x, wv.z, acc[0][2]);
            acc[0][3] = fmaf(av.x, wv.w, acc[0][3]);
            acc[1][0] = fmaf(av.y, wv.x, acc[1][0]);
            acc[1][1] = fmaf(av.y, wv.y, acc[1][1]);
            acc[1][2] = fmaf(av.y, wv.z, acc[1][2]);
            acc[1][3] = fmaf(av.y, wv.w, acc[1][3]);
            acc[2][0] = fmaf(av.z, wv.x, acc[2][0]);
            acc[2][1] = fmaf(av.z, wv.y, acc[2][1]);
            acc[2][2] = fmaf(av.z, wv.z, acc[2][2]);
            acc[2][3] = fmaf(av.z, wv.w, acc[2][3]);
            acc[3][0] = fmaf(av.w, wv.x, acc[3][0]);
            acc[3][1] = fmaf(av.w, wv.y, acc[3][1]);
            acc[3][2] = fmaf(av.w, wv.z, acc[3][2]);
            acc[3][3] = fmaf(av.w, wv.w, acc[3][3]);
        }
    }

    int orow = qb + (tq << 2);
    int ocol = db + (td << 2);
    float b0 = bq[ocol], b1 = bq[ocol + 1], b2 = bq[ocol + 2], b3 = bq[ocol + 3];
#pragma unroll
    for (int i = 0; i < 4; i++) {
        float4 o = { acc[i][0] + b0, acc[i][1] + b1, acc[i][2] + b2, acc[i][3] + b3 };
        *(float4*)(qp + (size_t)(orow + i) * 256 + ocol) = o;
    }
}

// ------------------------------------------------------- qk = qp @ Wk
__global__ __launch_bounds__(256) void k_qk2(const float* __restrict__ qp,
                                             const float* __restrict__ Wk,
                                             float* __restrict__ qk) {
    __shared__ float aT[32][68];
    __shared__ float wS[32][68];
    int qb = (blockIdx.x >> 2) << 6;
    int eb = (blockIdx.x & 3) << 6;
    int t = threadIdx.x;
    int tq = t >> 4, te = t & 15;

    int qq0 = t >> 3, qq1 = (t + 256) >> 3;
    int kk4a = (t & 7) << 2;

    float acc[4][4] = {{0.f}};

    for (int c = 0; c < 8; c++) {
        int k0 = c << 5;
        __syncthreads();
        {
            float4 v0 = *(const float4*)(qp + (size_t)(qb + qq0) * 256 + k0 + kk4a);
            float4 v1 = *(const float4*)(qp + (size_t)(qb + qq1) * 256 + k0 + kk4a);
            aT[kk4a + 0][qq0] = v0.x; aT[kk4a + 1][qq0] = v0.y;
            aT[kk4a + 2][qq0] = v0.z; aT[kk4a + 3][qq0] = v0.w;
            aT[kk4a + 0][qq1] = v1.x; aT[kk4a + 1][qq1] = v1.y;
            aT[kk4a + 2][qq1] = v1.z; aT[kk4a + 3][qq1] = v1.w;
        }
        {
            for (int i = t; i < 512; i += 256) {
                int kk = i >> 4, ee4 = (i & 15) << 2;
                float4 v = *(const float4*)(Wk + (size_t)(k0 + kk) * 256 + eb + ee4);
                *(float4*)&wS[kk][ee4] = v;
            }
        }
        __syncthreads();
#pragma unroll 8
        for (int kk = 0; kk < 32; kk++) {
            float4 av = *(const float4*)&aT[kk][tq << 2];
            float4 wv = *(const float4*)&wS[kk][te << 2];
            acc[0][0] = fmaf(av.x, wv.x, acc[0][0]);
            acc[0][1] = fmaf(av.x, wv.y, acc[0][1]);
            acc[0][2] = fmaf(av.x, wv.z, acc[0][2]);
            acc[0][3] = fmaf(av.x, wv.w, acc[0][3]);
            acc[1][0] = fmaf(av.y, wv.x, acc[1][0]);
            acc[1][1] = fmaf(av.y, wv.y, acc[1][1]);
            acc[1][2] = fmaf(av.y, wv.z, acc[1][2]);
            acc[1][3] = fmaf(av.y, wv.w, acc[1][3]);
            acc[2][0] = fmaf(av.z, wv.x, acc[2][0]);
            acc[2][1] = fmaf(av.z, wv.y, acc[2][1]);
            acc[2][2] = fmaf(av.z, wv.z, acc[2][2]);
            acc[2][3] = fmaf(av.z, wv.w, acc[2][3]);
            acc[3][0] = fmaf(av.w, wv.x, acc[3][0]);
            acc[3][1] = fmaf(av.w, wv.y, acc[3][1]);
            acc[3][2] = fmaf(av.w, wv.z, acc[3][2]);
            acc[3][3] = fmaf(av.w, wv.w, acc[3][3]);
        }
    }

    int orow = qb + (tq << 2);
    int ocol = eb + (te << 2);
#pragma unroll
    for (int i = 0; i < 4; i++) {
        float4 o = { acc[i][0], acc[i][1], acc[i][2], acc[i][3] };
        *(float4*)(qk + (size_t)(orow + i) * 256 + ocol) = o;
    }
}

// ------------------------------------------------------ bterm[q] = bk . qp[q]
__global__ __launch_bounds__(256) void k_bterm(const float* __restrict__ qp,
                                               const float* __restrict__ bk,
                                               float* __restrict__ bterm) {
    int q = blockIdx.x * 4 + (threadIdx.x >> 6);
    int lane = threadIdx.x & 63;
    float4 v = *(const float4*)(qp + (size_t)q * 256 + lane * 4);
    float4 b = *(const float4*)(bk + lane * 4);
    float s = fmaf(v.x, b.x, fmaf(v.y, b.y, fmaf(v.z, b.z, v.w * b.w)));
#pragma unroll
    for (int off = 32; off; off >>= 1) s += __shfl_xor(s, off);
    if (lane == 0) bterm[q] = s;
}

// -------------------- h transpose: hT4[row][j4][l] = (float4)h[row][l][4j4..4j4+3]
__global__ __launch_bounds__(256) void k_htr(const float* __restrict__ h,
                                             float4* __restrict__ hT4) {
    __shared__ float hsT[256][65];   // [d][l], pad 65 -> conflict-free reads
    int row = blockIdx.x;
    int t = threadIdx.x;
    const float4* h4 = (const float4*)(h + (size_t)row * 64 * 256);
    for (int i = t; i < 4096; i += 256) {          // coalesced global read
        int l = i >> 6, d4 = i & 63;
        float4 v = h4[i];
        hsT[d4 * 4 + 0][l] = v.x; hsT[d4 * 4 + 1][l] = v.y;
        hsT[d4 * 4 + 2][l] = v.z; hsT[d4 * 4 + 3][l] = v.w;
    }
    __syncthreads();
    float4* o4 = hT4 + (size_t)row * 4096;
    for (int i = t; i < 4096; i += 256) {          // coalesced global write
        int j4 = i >> 6, l = i & 63;
        float4 o = { hsT[4 * j4 + 0][l], hsT[4 * j4 + 1][l],
                     hsT[4 * j4 + 2][l], hsT[4 * j4 + 3][l] };
        o4[i] = o;
    }
}

// ------------------------------------ attention v4: wave per query, COALESCED h
__global__ __launch_bounds__(256) void k_attn4(const float4* __restrict__ hT4,
                                               const float* __restrict__ qk,
                                               const float* __restrict__ bterm,
                                               const float* __restrict__ xsum,
                                               const int* __restrict__ pos2grp,
                                               const int* __restrict__ msk,
                                               const int* __restrict__ idx,
                                               float* __restrict__ attn) {
    int wid  = threadIdx.x >> 6;
    int lane = threadIdx.x & 63;
    int bid = ((blockIdx.x & 7) << 8) | (blockIdx.x >> 3);   // XCD chunked swizzle
    int q = bid * 4 + wid;
    int row = idx[q];

    const float4* hT  = hT4 + (size_t)row * 4096;            // [j4][l]
    const float4* qk4 = (const float4*)(qk + (size_t)q * 256);  // wave-uniform
    float p = 0.f;
#pragma unroll 8
    for (int j4 = 0; j4 < 64; j4++) {
        float4 hv = hT[j4 * 64 + lane];                      // coalesced 1KB
        float4 qv = qk4[j4];
        p = fmaf(hv.x, qv.x, fmaf(hv.y, qv.y,
            fmaf(hv.z, qv.z, fmaf(hv.w, qv.w, p))));
    }
    int v = msk[row * 64 + lane];
    float s = v ? (p + bterm[q]) * 0.0625f : -INFINITY;

    float m = s;
#pragma unroll
    for (int off = 32; off; off >>= 1) m = fmaxf(m, __shfl_xor(m, off));
    float e = expf(s - m);
    float sum = e;
#pragma unroll
    for (int off = 32; off; off >>= 1) sum += __shfl_xor(sum, off);
    float a = e / sum;

    int g_l = pos2grp[row * 64 + lane];                      // coalesced once
    float acc = 0.f;
#pragma unroll 8
    for (int l = 0; l < 64; l++) {
        float al = __shfl(a, l);
        int g = __shfl(g_l, l);
        acc = fmaf(al, xsum[(size_t)g * 64 + lane], acc);    // coalesced 256B
    }
    attn[(size_t)q * 64 + lane] = acc;
}

// ------------------------------------ attention v3 (fallback if ws too small)
__global__ __launch_bounds__(256) void k_attn3(const float* __restrict__ h,
                                               const float* __restrict__ qk,
                                               const float* __restrict__ bterm,
                                               const float* __restrict__ xsum,
                                               const int* __restrict__ pos2grp,
                                               const int* __restrict__ msk,
                                               const int* __restrict__ idx,
                                               float* __restrict__ attn) {
    int wid  = threadIdx.x >> 6;
    int lane = threadIdx.x & 63;
    int bid = ((blockIdx.x & 7) << 8) | (blockIdx.x >> 3);
    int q = bid * 4 + wid;
    int row = idx[q];

    const float* hr  = h  + ((size_t)row * 64 + lane) * 256;
    const float* qkq = qk + (size_t)q * 256;
    float p = 0.f;
#pragma unroll 4
    for (int j = 0; j < 256; j += 4) {
        float4 hv = *(const float4*)(hr + j);
        float4 qv = *(const float4*)(qkq + j);
        p = fmaf(hv.x, qv.x, fmaf(hv.y, qv.y,
            fmaf(hv.z, qv.z, fmaf(hv.w, qv.w, p))));
    }
    int v = msk[row * 64 + lane];
    float s = v ? (p + bterm[q]) * 0.0625f : -INFINITY;

    float m = s;
#pragma unroll
    for (int off = 32; off; off >>= 1) m = fmaxf(m, __shfl_xor(m, off));
    float e = expf(s - m);
    float sum = e;
#pragma unroll
    for (int off = 32; off; off >>= 1) sum += __shfl_xor(sum, off);
    float a = e / sum;

    const int* p2g = pos2grp + row * 64;
    float acc = 0.f;
#pragma unroll 8
    for (int l = 0; l < 64; l++) {
        float al = __shfl(a, l);
        int g = p2g[l];
        acc = fmaf(al, xsum[(size_t)g * 64 + lane], acc);
    }
    attn[(size_t)q * 64 + lane] = acc;
}

// --------------------------- logit = cat(q_in, attn) @ Wrel^T + brel ; metrics
#define VSTRIDE 580
__global__ __launch_bounds__(256) void k_logit(const float* __restrict__ h,
                                               const float* __restrict__ Wrel,
                                               const float* __restrict__ brel,
                                               const int* __restrict__ idx,
                                               const int* __restrict__ src,
                                               const int* __restrict__ dst,
                                               const float* __restrict__ attn,
                                               const int* __restrict__ typ,
                                               float* __restrict__ out,
                                               int* __restrict__ em,
                                               int* __restrict__ eqcnt) {
    __shared__ float vs[16 * VSTRIDE];
    __shared__ int cnt;
    int qb = blockIdx.x * 16;
    if (threadIdx.x == 0) cnt = 0;
    for (int i = threadIdx.x; i < 16 * 576; i += 256) {
        int qq = i / 576, j = i - qq * 576;
        int gq = qb + qq;
        float v;
        if (j < 512) {
            int r = idx[gq];
            int pos = (j < 256) ? src[gq] : dst[gq];
            v = h[((size_t)r * 64 + pos) * 256 + (j & 255)];
        } else {
            v = attn[(size_t)gq * 64 + (j - 512)];
        }
        vs[qq * VSTRIDE + j] = v;
    }
    __syncthreads();

    int qq = threadIdx.x >> 4, tt = threadIdx.x & 15;
    const float* wr = Wrel + (size_t)tt * 576;
    const float* vv = vs + qq * VSTRIDE;
    float acc = 0.f;
    for (int j = 0; j < 576; j += 4) {
        float4 wv = *(const float4*)(wr + j);
        float4 xv = *(const float4*)(vv + j);
        acc = fmaf(wv.x, xv.x, fmaf(wv.y, xv.y,
              fmaf(wv.z, xv.z, fmaf(wv.w, xv.w, acc))));
    }
    acc += brel[tt];
    int gq = qb + qq;
    out[(size_t)gq * 16 + tt] = acc;

    int eq = ((acc > 0.f) == (typ[gq * 16 + tt] > 0)) ? 1 : 0;
    unsigned long long mask = __ballot(eq);
    int lane = threadIdx.x & 63;
    if ((lane & 15) == 0) {
        unsigned bits = (unsigned)((mask >> (lane & 48)) & 0xFFFFull);
        atomicAdd(&cnt, __popc(bits));
        int all = (bits == 0xFFFFu) ? 1 : 0;
        atomicMin(&em[idx[gq]], all);
    }
    __syncthreads();
    if (threadIdx.x == 0) atomicAdd(eqcnt, cnt);
}

// ---------------------------------------------------------------- finalize
__global__ void k_fin(const int* __restrict__ em, const int* __restrict__ eqcnt,
                      float* __restrict__ out) {
    __shared__ float ssum[512];
    int t = threadIdx.x;
    int v = em[t];
    out[131074 + t] = (float)v;
    ssum[t] = (float)v;
    __syncthreads();
    for (int s = 256; s; s >>= 1) {
        if (t < s) ssum[t] += ssum[t + s];
        __syncthreads();
    }
    if (t == 0) {
        out[131073] = ssum[0] / 512.0f;
        out[131072] = (float)(*eqcnt) / (float)(Q_ * NTYP);
    }
}

extern "C" void kernel_launch(void* const* d_in, const int* in_sizes, int n_in,
                              void* d_out, int out_size, void* d_ws, size_t ws_size,
                              hipStream_t stream) {
    const float* h    = (const float*)d_in[0];
    const float* tok  = (const float*)d_in[1];
    const float* Wq   = (const float*)d_in[2];
    const float* bq   = (const float*)d_in[3];
    const float* Wk   = (const float*)d_in[4];
    const float* bk   = (const float*)d_in[5];
    const float* Wrel = (const float*)d_in[6];
    const float* brel = (const float*)d_in[7];
    const int* mem     = (const int*)d_in[8];
    const int* grp     = (const int*)d_in[9];
    const int* pos2grp = (const int*)d_in[10];
    const int* msk     = (const int*)d_in[11];
    const int* idx     = (const int*)d_in[12];
    const int* src     = (const int*)d_in[13];
    const int* dst     = (const int*)d_in[14];
    const int* typ     = (const int*)d_in[15];
    float* out = (float*)d_out;

    char* ws = (char*)d_ws;
    float* xsum  = (float*)ws;                          // 8 MB
    float* qk    = (float*)(ws + (size_t)( 8 << 20));   // 8 MB
    float* qp    = (float*)(ws + (size_t)(16 << 20));   // 8 MB
    float* bterm = (float*)(ws + (size_t)(24 << 20));   // 32 KB
    float* attn  = (float*)(ws + (size_t)(25 << 20));   // 2 MB
    int* em      = (int*)  (ws + (size_t)(27 << 20));   // 2 KB
    int* eqcnt   = (int*)  (ws + (size_t)(27 << 20) + 4096);
    float4* hT4  = (float4*)(ws + (size_t)(28 << 20));  // 32 MB
    int* counts     = (int*)(ws + (size_t)(60 << 20));            // 128 KB
    int* offsets    = (int*)(ws + (size_t)(60 << 20) + (128 << 10)); // 128 KB
    int* cursor     = (int*)(ws + (size_t)(60 << 20) + (256 << 10)); // 128 KB
    int* sorted_mem = (int*)(ws + (size_t)(60 << 20) + (384 << 10)); // 1 MB
    bool use_tr   = ws_size >= ((size_t)(60 << 20));
    bool use_sort = ws_size >= ((size_t)(62 << 20));

    k_init<<<1, 512, 0, stream>>>(em, eqcnt);
    if (use_sort) {
        hipMemsetAsync(counts, 0, (size_t)NSEG * 4, stream);
        k_hist<<<NMEM / 256, 256, 0, stream>>>(grp, counts);
        k_scan<<<1, 1024, 0, stream>>>(counts, offsets, cursor);
        k_bucket<<<NMEM / 256, 256, 0, stream>>>(grp, mem, cursor, sorted_mem);
        k_gsum<<<NSEG / 4, 256, 0, stream>>>(tok, sorted_mem, offsets, counts, xsum);
    } else {
        hipMemsetAsync(xsum, 0, (size_t)NSEG * 64 * 4, stream);
        k_scatter<<<NMEM * 64 / 256, 256, 0, stream>>>(tok, mem, grp, xsum);
    }
    k_qp2<<<(Q_ / 64) * 4, 256, 0, stream>>>(h, Wq, bq, idx, src, dst, qp);
    k_qk2<<<(Q_ / 64) * 4, 256, 0, stream>>>(qp, Wk, qk);
    k_bterm<<<Q_ / 4, 256, 0, stream>>>(qp, bk, bterm);
    if (use_tr) {
        k_htr<<<N_, 256, 0, stream>>>(h, hT4);
        k_attn4<<<Q_ / 4, 256, 0, stream>>>(hT4, qk, bterm, xsum, pos2grp, msk, idx, attn);
    } else {
        k_attn3<<<Q_ / 4, 256, 0, stream>>>(h, qk, bterm, xsum, pos2grp, msk, idx, attn);
    }
    k_logit<<<Q_ / 16, 256, 0, stream>>>(h, Wrel, brel, idx, src, dst, attn, typ, out, em, eqcnt);
    k_fin<<<1, 512, 0, stream>>>(em, eqcnt, out);
}

// Round 9
// 342.383 us; speedup vs baseline: 1.0163x; 1.0163x over previous
//
#include <hip/hip_runtime.h>
#include <math.h>

#define N_    512
#define L_    64
#define DH    256
#define DX    64
#define Q_    8192
#define NTYP  16
#define NMEM  262144
#define NSEG  32768

// ---------------------------------------------------------------- init
__global__ void k_init(int* __restrict__ em, int* __restrict__ eqcnt) {
    int t = blockIdx.x * blockDim.x + threadIdx.x;
    if (t < N_) em[t] = 0x7fffffff;   // segment_min identity (int32 max)
    if (t == 0) *eqcnt = 0;
}

// ======================= segment-sum via counting sort (no f32 atomics) ====
__global__ __launch_bounds__(256) void k_hist(const int* __restrict__ grp,
                                              int* __restrict__ counts) {
    int e = blockIdx.x * 256 + threadIdx.x;
    atomicAdd(&counts[grp[e]], 1);
}

__global__ __launch_bounds__(1024) void k_scan(const int* __restrict__ counts,
                                               int* __restrict__ offsets,
                                               int* __restrict__ cursor) {
    __shared__ int ls[1024];
    int t = threadIdx.x;
    int c[32];
    int base = t * 32;
    int s = 0;
#pragma unroll
    for (int i = 0; i < 32; i++) { c[i] = counts[base + i]; s += c[i]; }
    ls[t] = s;
    __syncthreads();
    for (int off = 1; off < 1024; off <<= 1) {   // Hillis-Steele inclusive
        int v = (t >= off) ? ls[t - off] : 0;
        __syncthreads();
        ls[t] += v;
        __syncthreads();
    }
    int excl = (t == 0) ? 0 : ls[t - 1];
#pragma unroll
    for (int i = 0; i < 32; i++) {
        offsets[base + i] = excl;
        cursor[base + i] = excl;
        excl += c[i];
    }
}

__global__ __launch_bounds__(256) void k_bucket(const int* __restrict__ grp,
                                                const int* __restrict__ mem,
                                                int* __restrict__ cursor,
                                                int* __restrict__ sorted_mem) {
    int e = blockIdx.x * 256 + threadIdx.x;
    int g = grp[e];
    int pos = atomicAdd(&cursor[g], 1);
    sorted_mem[pos] = mem[e];
}

__global__ __launch_bounds__(256) void k_gsum(const float* __restrict__ tok,
                                              const int* __restrict__ sorted_mem,
                                              const int* __restrict__ offsets,
                                              const int* __restrict__ counts,
                                              float* __restrict__ xsum) {
    int g = blockIdx.x * 4 + (threadIdx.x >> 6);
    int lane = threadIdx.x & 63;
    int beg = offsets[g], cnt = counts[g];
    float acc = 0.f;
    for (int j = 0; j < cnt; j++) {
        int m = sorted_mem[beg + j];              // wave-uniform -> scalar
        acc += tok[(size_t)m * 64 + lane];        // coalesced 256B gather
    }
    xsum[(size_t)g * 64 + lane] = acc;
}

// ---------------------------------- fallback: atomic scatter (small ws only)
__global__ __launch_bounds__(256) void k_scatter(const float* __restrict__ tok,
                                                 const int* __restrict__ mem,
                                                 const int* __restrict__ grp,
                                                 float* __restrict__ xsum) {
    long tid = (long)blockIdx.x * 256 + threadIdx.x;
    int e = (int)(tid >> 6);
    int d = (int)(tid & 63);
    int m = mem[e];
    int g = grp[e];
    atomicAdd(&xsum[(size_t)g * 64 + d], tok[(size_t)m * 64 + d]);
}

// --------------------------- qp = cat(h[idx,src],h[idx,dst]) @ Wq^T + bq
__global__ __launch_bounds__(256) void k_qp2(const float* __restrict__ h,
                                             const float* __restrict__ Wq,
                                             const float* __restrict__ bq,
                                             const int* __restrict__ idx,
                                             const int* __restrict__ src,
                                             const int* __restrict__ dst,
                                             float* __restrict__ qp) {
    __shared__ float aT[32][68];
    __shared__ float wT[32][68];
    int qb = (blockIdx.x >> 2) << 6;
    int db = (blockIdx.x & 3) << 6;
    int t = threadIdx.x;
    int tq = t >> 4, td = t & 15;

    int qq0 = t >> 3, qq1 = (t + 256) >> 3;
    int g0 = qb + qq0, g1 = qb + qq1;
    int r0 = idx[g0], s0 = src[g0], e0 = dst[g0];
    int r1 = idx[g1], s1 = src[g1], e1 = dst[g1];
    int kk4a = (t & 7) << 2;

    float acc[4][4] = {{0.f}};

    for (int c = 0; c < 16; c++) {
        int k0 = c << 5;
        int half = (k0 < 256);
        __syncthreads();
        {
            const float* b0 = h + ((size_t)r0 * 64 + (half ? s0 : e0)) * 256 + (k0 & 255) + kk4a;
            const float* b1 = h + ((size_t)r1 * 64 + (half ? s1 : e1)) * 256 + (k0 & 255) + kk4a;
            float4 v0 = *(const float4*)b0;
            float4 v1 = *(const float4*)b1;
            aT[kk4a + 0][qq0] = v0.x; aT[kk4a + 1][qq0] = v0.y;
            aT[kk4a + 2][qq0] = v0.z; aT[kk4a + 3][qq0] = v0.w;
            aT[kk4a + 0][qq1] = v1.x; aT[kk4a + 1][qq1] = v1.y;
            aT[kk4a + 2][qq1] = v1.z; aT[kk4a + 3][qq1] = v1.w;
        }
        {
            for (int i = t; i < 512; i += 256) {
                int dd = i >> 3, kk4 = (i & 7) << 2;
                float4 v = *(const float4*)(Wq + (size_t)(db + dd) * 512 + k0 + kk4);
                wT[kk4 + 0][dd] = v.x; wT[kk4 + 1][dd] = v.y;
                wT[kk4 + 2][dd] = v.z; wT[kk4 + 3][dd] = v.w;
            }
        }
        __syncthreads();
#pragma unroll 8
        for (int kk = 0; kk < 32; kk++) {
            float4 av = *(const float4*)&aT[kk][tq << 2];
            float4 wv = *(const float4*)&wT[kk][td << 2];
            acc[0][0] = fmaf(av.x, wv.x, acc[0][0]);
            acc[0][1] = fmaf(av.x, wv.y, acc[0][1]);
            acc[0][2] = fmaf(av.x, wv.z, acc[0][2]);
            acc[0][3] = fmaf(av.x, wv.w, acc[0][3]);
            acc[1][0] = fmaf(av.y, wv.x, acc[1][0]);
            acc[1][1] = fmaf(av.y, wv.y, acc[1][1]);
            acc[1][2] = fmaf(av.y, wv.z, acc[1][2]);
            acc[1][3] = fmaf(av.y, wv.w, acc[1][3]);
            acc[2][0] = fmaf(av.z, wv.x, acc[2][0]);
            acc[2][1] = fmaf(av.z, wv.y, acc[2][1]);
            acc[2][2] = fmaf(av.z, wv.z, acc[2][2]);
            acc[2][3] = fmaf(av.z, wv.w, acc[2][3]);
            acc[3][0] = fmaf(av.w, wv.x, acc[3][0]);
            acc[3][1] = fmaf(av.w, wv.y, acc[3][1]);
            acc[3][2] = fmaf(av.w, wv.z, acc[3][2]);
            acc[3][3] = fmaf(av.w, wv.w, acc[3][3]);
        }
    }

    int orow = qb + (tq << 2);
    int ocol = db + (td << 2);
    float b0 = bq[ocol], b1 = bq[ocol + 1], b2 = bq[ocol + 2], b3 = bq[ocol + 3];
#pragma unroll
    for (int i = 0; i < 4; i++) {
        float4 o = { acc[i][0] + b0, acc[i][1] + b1, acc[i][2] + b2, acc[i][3] + b3 };
        *(float4*)(qp + (size_t)(orow + i) * 256 + ocol) = o;
    }
}

// ------------------------------------------------------- qk = qp @ Wk
__global__ __launch_bounds__(256) void k_qk2(const float* __restrict__ qp,
                                             const float* __restrict__ Wk,
                                             float* __restrict__ qk) {
    __shared__ float aT[32][68];
    __shared__ float wS[32][68];
    int qb = (blockIdx.x >> 2) << 6;
    int eb = (blockIdx.x & 3) << 6;
    int t = threadIdx.x;
    int tq = t >> 4, te = t & 15;

    int qq0 = t >> 3, qq1 = (t + 256) >> 3;
    int kk4a = (t & 7) << 2;

    float acc[4][4] = {{0.f}};

    for (int c = 0; c < 8; c++) {
        int k0 = c << 5;
        __syncthreads();
        {
            float4 v0 = *(const float4*)(qp + (size_t)(qb + qq0) * 256 + k0 + kk4a);
            float4 v1 = *(const float4*)(qp + (size_t)(qb + qq1) * 256 + k0 + kk4a);
            aT[kk4a + 0][qq0] = v0.x; aT[kk4a + 1][qq0] = v0.y;
            aT[kk4a + 2][qq0] = v0.z; aT[kk4a + 3][qq0] = v0.w;
            aT[kk4a + 0][qq1] = v1.x; aT[kk4a + 1][qq1] = v1.y;
            aT[kk4a + 2][qq1] = v1.z; aT[kk4a + 3][qq1] = v1.w;
        }
        {
            for (int i = t; i < 512; i += 256) {
                int kk = i >> 4, ee4 = (i & 15) << 2;
                float4 v = *(const float4*)(Wk + (size_t)(k0 + kk) * 256 + eb + ee4);
                *(float4*)&wS[kk][ee4] = v;
            }
        }
        __syncthreads();
#pragma unroll 8
        for (int kk = 0; kk < 32; kk++) {
            float4 av = *(const float4*)&aT[kk][tq << 2];
            float4 wv = *(const float4*)&wS[kk][te << 2];
            acc[0][0] = fmaf(av.x, wv.x, acc[0][0]);
            acc[0][1] = fmaf(av.x, wv.y, acc[0][1]);
            acc[0][2] = fmaf(av.x, wv.z, acc[0][2]);
            acc[0][3] = fmaf(av.x, wv.w, acc[0][3]);
            acc[1][0] = fmaf(av.y, wv.x, acc[1][0]);
            acc[1][1] = fmaf(av.y, wv.y, acc[1][1]);
            acc[1][2] = fmaf(av.y, wv.z, acc[1][2]);
            acc[1][3] = fmaf(av.y, wv.w, acc[1][3]);
            acc[2][0] = fmaf(av.z, wv.x, acc[2][0]);
            acc[2][1] = fmaf(av.z, wv.y, acc[2][1]);
            acc[2][2] = fmaf(av.z, wv.z, acc[2][2]);
            acc[2][3] = fmaf(av.z, wv.w, acc[2][3]);
            acc[3][0] = fmaf(av.w, wv.x, acc[3][0]);
            acc[3][1] = fmaf(av.w, wv.y, acc[3][1]);
            acc[3][2] = fmaf(av.w, wv.z, acc[3][2]);
            acc[3][3] = fmaf(av.w, wv.w, acc[3][3]);
        }
    }

    int orow = qb + (tq << 2);
    int ocol = eb + (te << 2);
#pragma unroll
    for (int i = 0; i < 4; i++) {
        float4 o = { acc[i][0], acc[i][1], acc[i][2], acc[i][3] };
        *(float4*)(qk + (size_t)(orow + i) * 256 + ocol) = o;
    }
}

// ------------------------------------------------------ bterm[q] = bk . qp[q]
__global__ __launch_bounds__(256) void k_bterm(const float* __restrict__ qp,
                                               const float* __restrict__ bk,
                                               float* __restrict__ bterm) {
    int q = blockIdx.x * 4 + (threadIdx.x >> 6);
    int lane = threadIdx.x & 63;
    float4 v = *(const float4*)(qp + (size_t)q * 256 + lane * 4);
    float4 b = *(const float4*)(bk + lane * 4);
    float s = fmaf(v.x, b.x, fmaf(v.y, b.y, fmaf(v.z, b.z, v.w * b.w)));
#pragma unroll
    for (int off = 32; off; off >>= 1) s += __shfl_xor(s, off);
    if (lane == 0) bterm[q] = s;
}

// -------------------- h transpose: hT4[row][j4][l] = (float4)h[row][l][4j4..4j4+3]
__global__ __launch_bounds__(256) void k_htr(const float* __restrict__ h,
                                             float4* __restrict__ hT4) {
    __shared__ float hsT[256][65];   // [d][l], pad 65 -> conflict-free reads
    int row = blockIdx.x;
    int t = threadIdx.x;
    const float4* h4 = (const float4*)(h + (size_t)row * 64 * 256);
    for (int i = t; i < 4096; i += 256) {          // coalesced global read
        int l = i >> 6, d4 = i & 63;
        float4 v = h4[i];
        hsT[d4 * 4 + 0][l] = v.x; hsT[d4 * 4 + 1][l] = v.y;
        hsT[d4 * 4 + 2][l] = v.z; hsT[d4 * 4 + 3][l] = v.w;
    }
    __syncthreads();
    float4* o4 = hT4 + (size_t)row * 4096;
    for (int i = t; i < 4096; i += 256) {          // coalesced global write
        int j4 = i >> 6, l = i & 63;
        float4 o = { hsT[4 * j4 + 0][l], hsT[4 * j4 + 1][l],
                     hsT[4 * j4 + 2][l], hsT[4 * j4 + 3][l] };
        o4[i] = o;
    }
}

// ------------------------------------ attention v4: wave per query, COALESCED h
__global__ __launch_bounds__(256) void k_attn4(const float4* __restrict__ hT4,
                                               const float* __restrict__ qk,
                                               const float* __restrict__ bterm,
                                               const float* __restrict__ xsum,
                                               const int* __restrict__ pos2grp,
                                               const int* __restrict__ msk,
                                               const int* __restrict__ idx,
                                               float* __restrict__ attn) {
    int wid  = threadIdx.x >> 6;
    int lane = threadIdx.x & 63;
    int bid = ((blockIdx.x & 7) << 8) | (blockIdx.x >> 3);   // XCD chunked swizzle
    int q = bid * 4 + wid;
    int row = idx[q];

    const float4* hT  = hT4 + (size_t)row * 4096;            // [j4][l]
    const float4* qk4 = (const float4*)(qk + (size_t)q * 256);  // wave-uniform
    float p = 0.f;
#pragma unroll 8
    for (int j4 = 0; j4 < 64; j4++) {
        float4 hv = hT[j4 * 64 + lane];                      // coalesced 1KB
        float4 qv = qk4[j4];
        p = fmaf(hv.x, qv.x, fmaf(hv.y, qv.y,
            fmaf(hv.z, qv.z, fmaf(hv.w, qv.w, p))));
    }
    int v = msk[row * 64 + lane];
    float s = v ? (p + bterm[q]) * 0.0625f : -INFINITY;

    float m = s;
#pragma unroll
    for (int off = 32; off; off >>= 1) m = fmaxf(m, __shfl_xor(m, off));
    float e = expf(s - m);
    float sum = e;
#pragma unroll
    for (int off = 32; off; off >>= 1) sum += __shfl_xor(sum, off);
    float a = e / sum;

    int g_l = pos2grp[row * 64 + lane];                      // coalesced once
    float acc = 0.f;
#pragma unroll 8
    for (int l = 0; l < 64; l++) {
        float al = __shfl(a, l);
        int g = __shfl(g_l, l);
        acc = fmaf(al, xsum[(size_t)g * 64 + lane], acc);    // coalesced 256B
    }
    attn[(size_t)q * 64 + lane] = acc;
}

// ------------------------------------ attention v3 (fallback if ws too small)
__global__ __launch_bounds__(256) void k_attn3(const float* __restrict__ h,
                                               const float* __restrict__ qk,
                                               const float* __restrict__ bterm,
                                               const float* __restrict__ xsum,
                                               const int* __restrict__ pos2grp,
                                               const int* __restrict__ msk,
                                               const int* __restrict__ idx,
                                               float* __restrict__ attn) {
    int wid  = threadIdx.x >> 6;
    int lane = threadIdx.x & 63;
    int bid = ((blockIdx.x & 7) << 8) | (blockIdx.x >> 3);
    int q = bid * 4 + wid;
    int row = idx[q];

    const float* hr  = h  + ((size_t)row * 64 + lane) * 256;
    const float* qkq = qk + (size_t)q * 256;
    float p = 0.f;
#pragma unroll 4
    for (int j = 0; j < 256; j += 4) {
        float4 hv = *(const float4*)(hr + j);
        float4 qv = *(const float4*)(qkq + j);
        p = fmaf(hv.x, qv.x, fmaf(hv.y, qv.y,
            fmaf(hv.z, qv.z, fmaf(hv.w, qv.w, p))));
    }
    int v = msk[row * 64 + lane];
    float s = v ? (p + bterm[q]) * 0.0625f : -INFINITY;

    float m = s;
#pragma unroll
    for (int off = 32; off; off >>= 1) m = fmaxf(m, __shfl_xor(m, off));
    float e = expf(s - m);
    float sum = e;
#pragma unroll
    for (int off = 32; off; off >>= 1) sum += __shfl_xor(sum, off);
    float a = e / sum;

    const int* p2g = pos2grp + row * 64;
    float acc = 0.f;
#pragma unroll 8
    for (int l = 0; l < 64; l++) {
        float al = __shfl(a, l);
        int g = p2g[l];
        acc = fmaf(al, xsum[(size_t)g * 64 + lane], acc);
    }
    attn[(size_t)q * 64 + lane] = acc;
}

// ------- logit v3: thread = (q, typ, slice); 2x waves + 4-acc ILP vs v2.
// 8 q/block, 1024 blocks -> 4 waves/SIMD (old: 2). Slices joined by shfl_xor(1).
#define VSTRIDE3 580
__global__ __launch_bounds__(256) void k_logit3(const float* __restrict__ h,
                                                const float* __restrict__ Wrel,
                                                const float* __restrict__ brel,
                                                const int* __restrict__ idx,
                                                const int* __restrict__ src,
                                                const int* __restrict__ dst,
                                                const float* __restrict__ attn,
                                                const int* __restrict__ typ,
                                                float* __restrict__ out,
                                                int* __restrict__ em,
                                                int* __restrict__ eqcnt) {
    __shared__ float vs[8 * VSTRIDE3];   // 18.6 KB
    __shared__ int cnt;
    int qb = blockIdx.x * 8;
    int t = threadIdx.x;
    if (t == 0) cnt = 0;
    for (int i = t; i < 8 * 576; i += 256) {
        int qq = i / 576, j = i - qq * 576;
        int gq = qb + qq;
        float v;
        if (j < 512) {
            int r = idx[gq];
            int pos = (j < 256) ? src[gq] : dst[gq];
            v = h[((size_t)r * 64 + pos) * 256 + (j & 255)];
        } else {
            v = attn[(size_t)gq * 64 + (j - 512)];
        }
        vs[qq * VSTRIDE3 + j] = v;
    }
    __syncthreads();

    int qq = t >> 5, tt = (t >> 1) & 15, sl = t & 1;
    const float* wr = Wrel + (size_t)tt * 576 + sl * 288;   // L1/L2 resident
    const float* vv = vs + qq * VSTRIDE3 + sl * 288;
    float a0 = 0.f, a1 = 0.f, a2 = 0.f, a3 = 0.f;   // 4 indep chains
    for (int j = 0; j < 288; j += 16) {
        float4 w0 = *(const float4*)(wr + j);
        float4 w1 = *(const float4*)(wr + j + 4);
        float4 w2 = *(const float4*)(wr + j + 8);
        float4 w3 = *(const float4*)(wr + j + 12);
        float4 x0 = *(const float4*)(vv + j);
        float4 x1 = *(const float4*)(vv + j + 4);
        float4 x2 = *(const float4*)(vv + j + 8);
        float4 x3 = *(const float4*)(vv + j + 12);
        a0 = fmaf(w0.x, x0.x, fmaf(w0.y, x0.y, fmaf(w0.z, x0.z, fmaf(w0.w, x0.w, a0))));
        a1 = fmaf(w1.x, x1.x, fmaf(w1.y, x1.y, fmaf(w1.z, x1.z, fmaf(w1.w, x1.w, a1))));
        a2 = fmaf(w2.x, x2.x, fmaf(w2.y, x2.y, fmaf(w2.z, x2.z, fmaf(w2.w, x2.w, a2))));
        a3 = fmaf(w3.x, x3.x, fmaf(w3.y, x3.y, fmaf(w3.z, x3.z, fmaf(w3.w, x3.w, a3))));
    }
    float acc = (a0 + a1) + (a2 + a3);
    acc += __shfl_xor(acc, 1);          // join the two slices; both lanes full
    acc += brel[tt];
    int gq = qb + qq;
    if (sl == 0) out[(size_t)gq * 16 + tt] = acc;

    int eq = ((acc > 0.f) == (typ[gq * 16 + tt] > 0)) ? 1 : 0;   // same on both lanes
    unsigned long long mask = __ballot(eq);     // bit-pairs per (tt)
    int lane = t & 63;
    if ((lane & 31) == 0) {             // one handler per query (32-lane group)
        unsigned bits = (unsigned)(mask >> (lane & 32));
        atomicAdd(&cnt, __popc(bits & 0x55555555u));
        int all = (bits == 0xFFFFFFFFu) ? 1 : 0;
        atomicMin(&em[idx[gq]], all);
    }
    __syncthreads();
    if (t == 0) atomicAdd(eqcnt, cnt);
}

// ---------------------------------------------------------------- finalize
__global__ void k_fin(const int* __restrict__ em, const int* __restrict__ eqcnt,
                      float* __restrict__ out) {
    __shared__ float ssum[512];
    int t = threadIdx.x;
    int v = em[t];
    out[131074 + t] = (float)v;
    ssum[t] = (float)v;
    __syncthreads();
    for (int s = 256; s; s >>= 1) {
        if (t < s) ssum[t] += ssum[t + s];
        __syncthreads();
    }
    if (t == 0) {
        out[131073] = ssum[0] / 512.0f;
        out[131072] = (float)(*eqcnt) / (float)(Q_ * NTYP);
    }
}

extern "C" void kernel_launch(void* const* d_in, const int* in_sizes, int n_in,
                              void* d_out, int out_size, void* d_ws, size_t ws_size,
                              hipStream_t stream) {
    const float* h    = (const float*)d_in[0];
    const float* tok  = (const float*)d_in[1];
    const float* Wq   = (const float*)d_in[2];
    const float* bq   = (const float*)d_in[3];
    const float* Wk   = (const float*)d_in[4];
    const float* bk   = (const float*)d_in[5];
    const float* Wrel = (const float*)d_in[6];
    const float* brel = (const float*)d_in[7];
    const int* mem     = (const int*)d_in[8];
    const int* grp     = (const int*)d_in[9];
    const int* pos2grp = (const int*)d_in[10];
    const int* msk     = (const int*)d_in[11];
    const int* idx     = (const int*)d_in[12];
    const int* src     = (const int*)d_in[13];
    const int* dst     = (const int*)d_in[14];
    const int* typ     = (const int*)d_in[15];
    float* out = (float*)d_out;

    char* ws = (char*)d_ws;
    float* xsum  = (float*)ws;                          // 8 MB
    float* qk    = (float*)(ws + (size_t)( 8 << 20));   // 8 MB
    float* qp    = (float*)(ws + (size_t)(16 << 20));   // 8 MB
    float* bterm = (float*)(ws + (size_t)(24 << 20));   // 32 KB
    float* attn  = (float*)(ws + (size_t)(25 << 20));   // 2 MB
    int* em      = (int*)  (ws + (size_t)(27 << 20));   // 2 KB
    int* eqcnt   = (int*)  (ws + (size_t)(27 << 20) + 4096);
    float4* hT4  = (float4*)(ws + (size_t)(28 << 20));  // 32 MB
    int* counts     = (int*)(ws + (size_t)(60 << 20));               // 128 KB
    int* offsets    = (int*)(ws + (size_t)(60 << 20) + (128 << 10)); // 128 KB
    int* cursor     = (int*)(ws + (size_t)(60 << 20) + (256 << 10)); // 128 KB
    int* sorted_mem = (int*)(ws + (size_t)(60 << 20) + (384 << 10)); // 1 MB
    bool use_tr   = ws_size >= ((size_t)(60 << 20));
    bool use_sort = ws_size >= ((size_t)(62 << 20));

    k_init<<<1, 512, 0, stream>>>(em, eqcnt);
    if (use_sort) {
        hipMemsetAsync(counts, 0, (size_t)NSEG * 4, stream);
        k_hist<<<NMEM / 256, 256, 0, stream>>>(grp, counts);
        k_scan<<<1, 1024, 0, stream>>>(counts, offsets, cursor);
        k_bucket<<<NMEM / 256, 256, 0, stream>>>(grp, mem, cursor, sorted_mem);
        k_gsum<<<NSEG / 4, 256, 0, stream>>>(tok, sorted_mem, offsets, counts, xsum);
    } else {
        hipMemsetAsync(xsum, 0, (size_t)NSEG * 64 * 4, stream);
        k_scatter<<<NMEM * 64 / 256, 256, 0, stream>>>(tok, mem, grp, xsum);
    }
    k_qp2<<<(Q_ / 64) * 4, 256, 0, stream>>>(h, Wq, bq, idx, src, dst, qp);
    k_qk2<<<(Q_ / 64) * 4, 256, 0, stream>>>(qp, Wk, qk);
    k_bterm<<<Q_ / 4, 256, 0, stream>>>(qp, bk, bterm);
    if (use_tr) {
        k_htr<<<N_, 256, 0, stream>>>(h, hT4);
        k_attn4<<<Q_ / 4, 256, 0, stream>>>(hT4, qk, bterm, xsum, pos2grp, msk, idx, attn);
    } else {
        k_attn3<<<Q_ / 4, 256, 0, stream>>>(h, qk, bterm, xsum, pos2grp, msk, idx, attn);
    }
    k_logit3<<<Q_ / 8, 256, 0, stream>>>(h, Wrel, brel, idx, src, dst, attn, typ, out, em, eqcnt);
    k_fin<<<1, 512, 0, stream>>>(em, eqcnt, out);
}

// Round 10
// 311.804 us; speedup vs baseline: 1.1160x; 1.0981x over previous
//
#include <hip/hip_runtime.h>
#include <math.h>

#define N_    512
#define L_    64
#define DH    256
#define DX    64
#define Q_    8192
#define NTYP  16
#define NMEM  262144
#define NSEG  32768

typedef short bf16x8 __attribute__((ext_vector_type(8)));
typedef float f32x4  __attribute__((ext_vector_type(4)));

__device__ inline ushort f2bf(float x) {            // f32 -> bf16 RNE
    unsigned u = __float_as_uint(x);
    unsigned r = u + 0x7FFFu + ((u >> 16) & 1u);
    return (ushort)(r >> 16);
}

// ---------------------------------------------------------------- init
__global__ void k_init(int* __restrict__ em, int* __restrict__ eqcnt) {
    int t = blockIdx.x * blockDim.x + threadIdx.x;
    if (t < N_) em[t] = 0x7fffffff;   // segment_min identity (int32 max)
    if (t == 0) *eqcnt = 0;
}

// ======================= segment-sum via counting sort (no f32 atomics) ====
__global__ __launch_bounds__(256) void k_hist(const int* __restrict__ grp,
                                              int* __restrict__ counts) {
    int e = blockIdx.x * 256 + threadIdx.x;
    atomicAdd(&counts[grp[e]], 1);
}

__global__ __launch_bounds__(1024) void k_scan(const int* __restrict__ counts,
                                               int* __restrict__ offsets,
                                               int* __restrict__ cursor) {
    __shared__ int ls[1024];
    int t = threadIdx.x;
    int c[32];
    int base = t * 32;
    int s = 0;
#pragma unroll
    for (int i = 0; i < 32; i++) { c[i] = counts[base + i]; s += c[i]; }
    ls[t] = s;
    __syncthreads();
    for (int off = 1; off < 1024; off <<= 1) {   // Hillis-Steele inclusive
        int v = (t >= off) ? ls[t - off] : 0;
        __syncthreads();
        ls[t] += v;
        __syncthreads();
    }
    int excl = (t == 0) ? 0 : ls[t - 1];
#pragma unroll
    for (int i = 0; i < 32; i++) {
        offsets[base + i] = excl;
        cursor[base + i] = excl;
        excl += c[i];
    }
}

__global__ __launch_bounds__(256) void k_bucket(const int* __restrict__ grp,
                                                const int* __restrict__ mem,
                                                int* __restrict__ cursor,
                                                int* __restrict__ sorted_mem) {
    int e = blockIdx.x * 256 + threadIdx.x;
    int g = grp[e];
    int pos = atomicAdd(&cursor[g], 1);
    sorted_mem[pos] = mem[e];
}

__global__ __launch_bounds__(256) void k_gsum(const float* __restrict__ tok,
                                              const int* __restrict__ sorted_mem,
                                              const int* __restrict__ offsets,
                                              const int* __restrict__ counts,
                                              float* __restrict__ xsum) {
    int g = blockIdx.x * 4 + (threadIdx.x >> 6);
    int lane = threadIdx.x & 63;
    int beg = offsets[g], cnt = counts[g];
    float acc = 0.f;
    for (int j = 0; j < cnt; j++) {
        int m = sorted_mem[beg + j];              // wave-uniform -> scalar
        acc += tok[(size_t)m * 64 + lane];        // coalesced 256B gather
    }
    xsum[(size_t)g * 64 + lane] = acc;
}

// --------------------- weight conversion: Wq -> bf16, Wk -> bf16 transposed
__global__ __launch_bounds__(256) void k_wcvt(const float* __restrict__ Wq,
                                              const float* __restrict__ Wk,
                                              ushort* __restrict__ Wqbf,
                                              ushort* __restrict__ WkTbf) {
    int i = blockIdx.x * 256 + threadIdx.x;       // grid 512 blocks
    if (i < 131072) Wqbf[i] = f2bf(Wq[i]);        // same layout [d][k], k=512
    if (i < 65536) {
        int kk = i >> 8, e = i & 255;
        WkTbf[e * 256 + kk] = f2bf(Wk[i]);        // [e][k]
    }
}

// --------------------- q_in gather -> bf16: qin[q][0..255]=h[r,src], [256..511]=h[r,dst]
__global__ __launch_bounds__(256) void k_qin(const float* __restrict__ h,
                                             const int* __restrict__ idx,
                                             const int* __restrict__ src,
                                             const int* __restrict__ dst,
                                             ushort* __restrict__ qin) {
    int q = blockIdx.x * 2 + (threadIdx.x >> 7);
    int t = threadIdx.x & 127;                    // 128 thr/query, float4 each
    int r = idx[q];
    int pos = (t < 64) ? src[q] : dst[q];
    float4 v = *(const float4*)(h + ((size_t)r * 64 + pos) * 256 + (t & 63) * 4);
    ushort4 o = { f2bf(v.x), f2bf(v.y), f2bf(v.z), f2bf(v.w) };
    *(ushort4*)(qin + (size_t)q * 512 + t * 4) = o;
}

// --------------------- qp_bf = qin @ Wq^T + bq   (bf16 MFMA, f32 acc)
// block 64q x 64d, 4 waves, wave = 32x32 tile; no LDS.
// frag layouts (HW-verified m89): A row=l&15,k=(l>>4)*8+j; B col=l&15; D row=(l>>4)*4+r,col=l&15
__global__ __launch_bounds__(256) void k_gqp(const ushort* __restrict__ qin,
                                             const ushort* __restrict__ Wqbf,
                                             const float* __restrict__ bq,
                                             ushort* __restrict__ qp_bf) {
    int w = threadIdx.x >> 6, l = threadIdx.x & 63;
    int qb = (blockIdx.x >> 2) * 64 + (w >> 1) * 32;
    int db = (blockIdx.x & 3) * 64 + (w & 1) * 32;
    int lr = l & 15, lk = (l >> 4) * 8;
    f32x4 a00 = {0.f,0.f,0.f,0.f}, a01 = a00, a10 = a00, a11 = a00;
#pragma unroll 4
    for (int k0 = 0; k0 < 512; k0 += 32) {
        bf16x8 fa0 = *(const bf16x8*)(qin + (size_t)(qb + lr) * 512 + k0 + lk);
        bf16x8 fa1 = *(const bf16x8*)(qin + (size_t)(qb + 16 + lr) * 512 + k0 + lk);
        bf16x8 fb0 = *(const bf16x8*)(Wqbf + (size_t)(db + lr) * 512 + k0 + lk);
        bf16x8 fb1 = *(const bf16x8*)(Wqbf + (size_t)(db + 16 + lr) * 512 + k0 + lk);
        a00 = __builtin_amdgcn_mfma_f32_16x16x32_bf16(fa0, fb0, a00, 0, 0, 0);
        a01 = __builtin_amdgcn_mfma_f32_16x16x32_bf16(fa0, fb1, a01, 0, 0, 0);
        a10 = __builtin_amdgcn_mfma_f32_16x16x32_bf16(fa1, fb0, a10, 0, 0, 0);
        a11 = __builtin_amdgcn_mfma_f32_16x16x32_bf16(fa1, fb1, a11, 0, 0, 0);
    }
    int orow = (l >> 4) * 2, ocol = l & 15;   // row=(l>>4)*4+r
    float b0 = bq[db + ocol], b1 = bq[db + 16 + ocol];
#pragma unroll
    for (int r = 0; r < 4; r++) {
        int row = (l >> 4) * 4 + r;
        qp_bf[(size_t)(qb + row) * 256 + db + ocol]           = f2bf(a00[r] + b0);
        qp_bf[(size_t)(qb + row) * 256 + db + 16 + ocol]      = f2bf(a01[r] + b1);
        qp_bf[(size_t)(qb + 16 + row) * 256 + db + ocol]      = f2bf(a10[r] + b0);
        qp_bf[(size_t)(qb + 16 + row) * 256 + db + 16 + ocol] = f2bf(a11[r] + b1);
    }
    (void)orow;
}

// --------------------- qk = qp_bf @ Wk  (f32 out; B from WkT so frags contiguous)
__global__ __launch_bounds__(256) void k_gqk(const ushort* __restrict__ qp_bf,
                                             const ushort* __restrict__ WkTbf,
                                             float* __restrict__ qk) {
    int w = threadIdx.x >> 6, l = threadIdx.x & 63;
    int qb = (blockIdx.x >> 2) * 64 + (w >> 1) * 32;
    int eb = (blockIdx.x & 3) * 64 + (w & 1) * 32;
    int lr = l & 15, lk = (l >> 4) * 8;
    f32x4 a00 = {0.f,0.f,0.f,0.f}, a01 = a00, a10 = a00, a11 = a00;
#pragma unroll 4
    for (int k0 = 0; k0 < 256; k0 += 32) {
        bf16x8 fa0 = *(const bf16x8*)(qp_bf + (size_t)(qb + lr) * 256 + k0 + lk);
        bf16x8 fa1 = *(const bf16x8*)(qp_bf + (size_t)(qb + 16 + lr) * 256 + k0 + lk);
        bf16x8 fb0 = *(const bf16x8*)(WkTbf + (size_t)(eb + lr) * 256 + k0 + lk);
        bf16x8 fb1 = *(const bf16x8*)(WkTbf + (size_t)(eb + 16 + lr) * 256 + k0 + lk);
        a00 = __builtin_amdgcn_mfma_f32_16x16x32_bf16(fa0, fb0, a00, 0, 0, 0);
        a01 = __builtin_amdgcn_mfma_f32_16x16x32_bf16(fa0, fb1, a01, 0, 0, 0);
        a10 = __builtin_amdgcn_mfma_f32_16x16x32_bf16(fa1, fb0, a10, 0, 0, 0);
        a11 = __builtin_amdgcn_mfma_f32_16x16x32_bf16(fa1, fb1, a11, 0, 0, 0);
    }
    int ocol = l & 15;
#pragma unroll
    for (int r = 0; r < 4; r++) {
        int row = (l >> 4) * 4 + r;
        qk[(size_t)(qb + row) * 256 + eb + ocol]           = a00[r];
        qk[(size_t)(qb + row) * 256 + eb + 16 + ocol]      = a01[r];
        qk[(size_t)(qb + 16 + row) * 256 + eb + ocol]      = a10[r];
        qk[(size_t)(qb + 16 + row) * 256 + eb + 16 + ocol] = a11[r];
    }
}

// -------------------- h transpose: hT4[row][j4][l] = (float4)h[row][l][4j4..4j4+3]
__global__ __launch_bounds__(256) void k_htr(const float* __restrict__ h,
                                             float4* __restrict__ hT4) {
    __shared__ float hsT[256][65];   // [d][l], pad 65 -> conflict-free reads
    int row = blockIdx.x;
    int t = threadIdx.x;
    const float4* h4 = (const float4*)(h + (size_t)row * 64 * 256);
    for (int i = t; i < 4096; i += 256) {          // coalesced global read
        int l = i >> 6, d4 = i & 63;
        float4 v = h4[i];
        hsT[d4 * 4 + 0][l] = v.x; hsT[d4 * 4 + 1][l] = v.y;
        hsT[d4 * 4 + 2][l] = v.z; hsT[d4 * 4 + 3][l] = v.w;
    }
    __syncthreads();
    float4* o4 = hT4 + (size_t)row * 4096;
    for (int i = t; i < 4096; i += 256) {          // coalesced global write
        int j4 = i >> 6, l = i & 63;
        float4 o = { hsT[4 * j4 + 0][l], hsT[4 * j4 + 1][l],
                     hsT[4 * j4 + 2][l], hsT[4 * j4 + 3][l] };
        o4[i] = o;
    }
}

// ------------------------------------ attention: wave per query, coalesced h
// NOTE: bk.qp term dropped -- constant per query across l, softmax shift-invariant.
__global__ __launch_bounds__(256) void k_attn4(const float4* __restrict__ hT4,
                                               const float* __restrict__ qk,
                                               const float* __restrict__ xsum,
                                               const int* __restrict__ pos2grp,
                                               const int* __restrict__ msk,
                                               const int* __restrict__ idx,
                                               float* __restrict__ attn) {
    int wid  = threadIdx.x >> 6;
    int lane = threadIdx.x & 63;
    int bid = ((blockIdx.x & 7) << 8) | (blockIdx.x >> 3);   // XCD chunked swizzle
    int q = bid * 4 + wid;
    int row = idx[q];

    const float4* hT  = hT4 + (size_t)row * 4096;            // [j4][l]
    const float4* qk4 = (const float4*)(qk + (size_t)q * 256);  // wave-uniform
    float p = 0.f;
#pragma unroll 8
    for (int j4 = 0; j4 < 64; j4++) {
        float4 hv = hT[j4 * 64 + lane];                      // coalesced 1KB
        float4 qv = qk4[j4];
        p = fmaf(hv.x, qv.x, fmaf(hv.y, qv.y,
            fmaf(hv.z, qv.z, fmaf(hv.w, qv.w, p))));
    }
    int v = msk[row * 64 + lane];
    float s = v ? p * 0.0625f : -INFINITY;

    float m = s;
#pragma unroll
    for (int off = 32; off; off >>= 1) m = fmaxf(m, __shfl_xor(m, off));
    float e = expf(s - m);
    float sum = e;
#pragma unroll
    for (int off = 32; off; off >>= 1) sum += __shfl_xor(sum, off);
    float a = e / sum;

    int g_l = pos2grp[row * 64 + lane];                      // coalesced once
    float acc = 0.f;
#pragma unroll 8
    for (int l = 0; l < 64; l++) {
        float al = __shfl(a, l);
        int g = __shfl(g_l, l);
        acc = fmaf(al, xsum[(size_t)g * 64 + lane], acc);    // coalesced 256B
    }
    attn[(size_t)q * 64 + lane] = acc;
}

// ------- logit: thread = (q, typ, slice); 4 waves/SIMD + 4-acc ILP
#define VSTRIDE3 580
__global__ __launch_bounds__(256) void k_logit3(const float* __restrict__ h,
                                                const float* __restrict__ Wrel,
                                                const float* __restrict__ brel,
                                                const int* __restrict__ idx,
                                                const int* __restrict__ src,
                                                const int* __restrict__ dst,
                                                const float* __restrict__ attn,
                                                const int* __restrict__ typ,
                                                float* __restrict__ out,
                                                int* __restrict__ em,
                                                int* __restrict__ eqcnt) {
    __shared__ float vs[8 * VSTRIDE3];   // 18.6 KB
    __shared__ int cnt;
    int qb = blockIdx.x * 8;
    int t = threadIdx.x;
    if (t == 0) cnt = 0;
    for (int i = t; i < 8 * 576; i += 256) {
        int qq = i / 576, j = i - qq * 576;
        int gq = qb + qq;
        float v;
        if (j < 512) {
            int r = idx[gq];
            int pos = (j < 256) ? src[gq] : dst[gq];
            v = h[((size_t)r * 64 + pos) * 256 + (j & 255)];
        } else {
            v = attn[(size_t)gq * 64 + (j - 512)];
        }
        vs[qq * VSTRIDE3 + j] = v;
    }
    __syncthreads();

    int qq = t >> 5, tt = (t >> 1) & 15, sl = t & 1;
    const float* wr = Wrel + (size_t)tt * 576 + sl * 288;
    const float* vv = vs + qq * VSTRIDE3 + sl * 288;
    float a0 = 0.f, a1 = 0.f, a2 = 0.f, a3 = 0.f;
    for (int j = 0; j < 288; j += 16) {
        float4 w0 = *(const float4*)(wr + j);
        float4 w1 = *(const float4*)(wr + j + 4);
        float4 w2 = *(const float4*)(wr + j + 8);
        float4 w3 = *(const float4*)(wr + j + 12);
        float4 x0 = *(const float4*)(vv + j);
        float4 x1 = *(const float4*)(vv + j + 4);
        float4 x2 = *(const float4*)(vv + j + 8);
        float4 x3 = *(const float4*)(vv + j + 12);
        a0 = fmaf(w0.x, x0.x, fmaf(w0.y, x0.y, fmaf(w0.z, x0.z, fmaf(w0.w, x0.w, a0))));
        a1 = fmaf(w1.x, x1.x, fmaf(w1.y, x1.y, fmaf(w1.z, x1.z, fmaf(w1.w, x1.w, a1))));
        a2 = fmaf(w2.x, x2.x, fmaf(w2.y, x2.y, fmaf(w2.z, x2.z, fmaf(w2.w, x2.w, a2))));
        a3 = fmaf(w3.x, x3.x, fmaf(w3.y, x3.y, fmaf(w3.z, x3.z, fmaf(w3.w, x3.w, a3))));
    }
    float acc = (a0 + a1) + (a2 + a3);
    acc += __shfl_xor(acc, 1);
    acc += brel[tt];
    int gq = qb + qq;
    if (sl == 0) out[(size_t)gq * 16 + tt] = acc;

    int eq = ((acc > 0.f) == (typ[gq * 16 + tt] > 0)) ? 1 : 0;
    unsigned long long mask = __ballot(eq);
    int lane = t & 63;
    if ((lane & 31) == 0) {
        unsigned bits = (unsigned)(mask >> (lane & 32));
        atomicAdd(&cnt, __popc(bits & 0x55555555u));
        int all = (bits == 0xFFFFFFFFu) ? 1 : 0;
        atomicMin(&em[idx[gq]], all);
    }
    __syncthreads();
    if (t == 0) atomicAdd(eqcnt, cnt);
}

// ---------------------------------------------------------------- finalize
__global__ void k_fin(const int* __restrict__ em, const int* __restrict__ eqcnt,
                      float* __restrict__ out) {
    __shared__ float ssum[512];
    int t = threadIdx.x;
    int v = em[t];
    out[131074 + t] = (float)v;
    ssum[t] = (float)v;
    __syncthreads();
    for (int s = 256; s; s >>= 1) {
        if (t < s) ssum[t] += ssum[t + s];
        __syncthreads();
    }
    if (t == 0) {
        out[131073] = ssum[0] / 512.0f;
        out[131072] = (float)(*eqcnt) / (float)(Q_ * NTYP);
    }
}

extern "C" void kernel_launch(void* const* d_in, const int* in_sizes, int n_in,
                              void* d_out, int out_size, void* d_ws, size_t ws_size,
                              hipStream_t stream) {
    const float* h    = (const float*)d_in[0];
    const float* tok  = (const float*)d_in[1];
    const float* Wq   = (const float*)d_in[2];
    const float* bq   = (const float*)d_in[3];
    const float* Wk   = (const float*)d_in[4];
    const float* Wrel = (const float*)d_in[6];
    const float* brel = (const float*)d_in[7];
    const int* mem     = (const int*)d_in[8];
    const int* grp     = (const int*)d_in[9];
    const int* pos2grp = (const int*)d_in[10];
    const int* msk     = (const int*)d_in[11];
    const int* idx     = (const int*)d_in[12];
    const int* src     = (const int*)d_in[13];
    const int* dst     = (const int*)d_in[14];
    const int* typ     = (const int*)d_in[15];
    float* out = (float*)d_out;

    char* ws = (char*)d_ws;
    float* xsum   = (float*)ws;                           // 0..8 MB
    float* qk     = (float*)(ws + (size_t)( 8 << 20));    // 8..16 MB
    ushort* qin   = (ushort*)(ws + (size_t)(16 << 20));   // 16..24 MB (bf16)
    float* attn   = (float*)(ws + (size_t)(16 << 20));    // reuse after k_gqp (attn4 runs later)
    ushort* qp_bf = (ushort*)(ws + (size_t)(24 << 20));   // 24..28 MB
    float4* hT4   = (float4*)(ws + (size_t)(28 << 20));   // 28..60 MB
    int* counts     = (int*)(ws + (size_t)(60 << 20));               // 128 KB
    int* offsets    = (int*)(ws + (size_t)(60 << 20) + (128 << 10)); // 128 KB
    int* cursor     = (int*)(ws + (size_t)(60 << 20) + (256 << 10)); // 128 KB
    int* sorted_mem = (int*)(ws + (size_t)(60 << 20) + (384 << 10)); // 1 MB
    int* em         = (int*)(ws + (size_t)(61 << 20) + (512 << 10)); // 2 KB
    int* eqcnt      = (int*)(ws + (size_t)(61 << 20) + (516 << 10));
    ushort* Wqbf    = (ushort*)(ws + (size_t)(61 << 20) + (520 << 10)); // 256 KB
    ushort* WkTbf   = (ushort*)(ws + (size_t)(61 << 20) + (776 << 10)); // 128 KB

    k_init<<<1, 512, 0, stream>>>(em, eqcnt);
    hipMemsetAsync(counts, 0, (size_t)NSEG * 4, stream);
    k_hist<<<NMEM / 256, 256, 0, stream>>>(grp, counts);
    k_scan<<<1, 1024, 0, stream>>>(counts, offsets, cursor);
    k_bucket<<<NMEM / 256, 256, 0, stream>>>(grp, mem, cursor, sorted_mem);
    k_gsum<<<NSEG / 4, 256, 0, stream>>>(tok, sorted_mem, offsets, counts, xsum);
    k_wcvt<<<512, 256, 0, stream>>>(Wq, Wk, Wqbf, WkTbf);
    k_qin<<<Q_ / 2, 256, 0, stream>>>(h, idx, src, dst, qin);
    k_gqp<<<(Q_ / 64) * 4, 256, 0, stream>>>(qin, Wqbf, bq, qp_bf);
    k_gqk<<<(Q_ / 64) * 4, 256, 0, stream>>>(qp_bf, WkTbf, qk);
    k_htr<<<N_, 256, 0, stream>>>(h, hT4);
    k_attn4<<<Q_ / 4, 256, 0, stream>>>(hT4, qk, xsum, pos2grp, msk, idx, attn);
    k_logit3<<<Q_ / 8, 256, 0, stream>>>(h, Wrel, brel, idx, src, dst, attn, typ, out, em, eqcnt);
    k_fin<<<1, 512, 0, stream>>>(em, eqcnt, out);
}

// Round 12
// 274.491 us; speedup vs baseline: 1.2677x; 1.1359x over previous
//
#include <hip/hip_runtime.h>
#include <math.h>

#define N_    512
#define L_    64
#define DH    256
#define DX    64
#define Q_    8192
#define NTYP  16
#define NMEM  262144
#define NSEG  32768

typedef short bf16x8 __attribute__((ext_vector_type(8)));
typedef float f32x4  __attribute__((ext_vector_type(4)));

__device__ inline ushort f2bf(float x) {            // f32 -> bf16 RNE
    unsigned u = __float_as_uint(x);
    unsigned r = u + 0x7FFFu + ((u >> 16) & 1u);
    return (ushort)(r >> 16);
}

// ---------------------------------------------------------------- init
__global__ void k_init(int* __restrict__ em, int* __restrict__ eqcnt) {
    int t = blockIdx.x * blockDim.x + threadIdx.x;
    if (t < N_) em[t] = 0x7fffffff;   // segment_min identity (int32 max)
    if (t == 0) *eqcnt = 0;
}

// ======================= segment-sum via counting sort (no f32 atomics) ====
__global__ __launch_bounds__(256) void k_hist(const int* __restrict__ grp,
                                              int* __restrict__ counts) {
    int e = blockIdx.x * 256 + threadIdx.x;
    atomicAdd(&counts[grp[e]], 1);
}

__global__ __launch_bounds__(1024) void k_scan(const int* __restrict__ counts,
                                               int* __restrict__ offsets,
                                               int* __restrict__ cursor) {
    __shared__ int ls[1024];
    int t = threadIdx.x;
    int c[32];
    int base = t * 32;
    int s = 0;
#pragma unroll
    for (int i = 0; i < 32; i++) { c[i] = counts[base + i]; s += c[i]; }
    ls[t] = s;
    __syncthreads();
    for (int off = 1; off < 1024; off <<= 1) {   // Hillis-Steele inclusive
        int v = (t >= off) ? ls[t - off] : 0;
        __syncthreads();
        ls[t] += v;
        __syncthreads();
    }
    int excl = (t == 0) ? 0 : ls[t - 1];
#pragma unroll
    for (int i = 0; i < 32; i++) {
        offsets[base + i] = excl;
        cursor[base + i] = excl;
        excl += c[i];
    }
}

__global__ __launch_bounds__(256) void k_bucket(const int* __restrict__ grp,
                                                const int* __restrict__ mem,
                                                int* __restrict__ cursor,
                                                int* __restrict__ sorted_mem) {
    int e = blockIdx.x * 256 + threadIdx.x;
    int g = grp[e];
    int pos = atomicAdd(&cursor[g], 1);
    sorted_mem[pos] = mem[e];
}

__global__ __launch_bounds__(256) void k_gsum(const float* __restrict__ tok,
                                              const int* __restrict__ sorted_mem,
                                              const int* __restrict__ offsets,
                                              const int* __restrict__ counts,
                                              float* __restrict__ xsum) {
    int g = blockIdx.x * 4 + (threadIdx.x >> 6);
    int lane = threadIdx.x & 63;
    int beg = offsets[g], cnt = counts[g];
    float acc = 0.f;
    for (int j = 0; j < cnt; j++) {
        int m = sorted_mem[beg + j];              // wave-uniform -> scalar
        acc += tok[(size_t)m * 64 + lane];        // coalesced 256B gather
    }
    xsum[(size_t)g * 64 + lane] = acc;
}

// ------ weight conversion: Wq -> bf16, Wk -> bf16 transposed, Wrel -> bf16
__global__ __launch_bounds__(256) void k_wcvt(const float* __restrict__ Wq,
                                              const float* __restrict__ Wk,
                                              const float* __restrict__ Wrel,
                                              ushort* __restrict__ Wqbf,
                                              ushort* __restrict__ WkTbf,
                                              ushort* __restrict__ Wrelbf) {
    int i = blockIdx.x * 256 + threadIdx.x;       // grid 512 blocks
    if (i < 131072) Wqbf[i] = f2bf(Wq[i]);        // [d][k], k=512
    if (i < 65536) {
        int kk = i >> 8, e = i & 255;
        WkTbf[e * 256 + kk] = f2bf(Wk[i]);        // [e][k]
    }
    if (i < 9216) Wrelbf[i] = f2bf(Wrel[i]);      // [typ][k], k=576
}

// --------------------- q_in gather -> bf16: qin[q][0..255]=h[r,src], [256..511]=h[r,dst]
__global__ __launch_bounds__(256) void k_qin(const float* __restrict__ h,
                                             const int* __restrict__ idx,
                                             const int* __restrict__ src,
                                             const int* __restrict__ dst,
                                             ushort* __restrict__ qin) {
    int q = blockIdx.x * 2 + (threadIdx.x >> 7);
    int t = threadIdx.x & 127;                    // 128 thr/query, float4 each
    int r = idx[q];
    int pos = (t < 64) ? src[q] : dst[q];
    float4 v = *(const float4*)(h + ((size_t)r * 64 + pos) * 256 + (t & 63) * 4);
    ushort4 o = { f2bf(v.x), f2bf(v.y), f2bf(v.z), f2bf(v.w) };
    *(ushort4*)(qin + (size_t)q * 512 + t * 4) = o;
}

// --------------------- qp_bf = qin @ Wq^T + bq   (bf16 MFMA, f32 acc)
// frag layouts (HW-verified m89): A row=l&15,k=(l>>4)*8+j; B col=l&15; D row=(l>>4)*4+r,col=l&15
__global__ __launch_bounds__(256) void k_gqp(const ushort* __restrict__ qin,
                                             const ushort* __restrict__ Wqbf,
                                             const float* __restrict__ bq,
                                             ushort* __restrict__ qp_bf) {
    int w = threadIdx.x >> 6, l = threadIdx.x & 63;
    int qb = (blockIdx.x >> 2) * 64 + (w >> 1) * 32;
    int db = (blockIdx.x & 3) * 64 + (w & 1) * 32;
    int lr = l & 15, lk = (l >> 4) * 8;
    f32x4 a00 = {0.f,0.f,0.f,0.f}, a01 = a00, a10 = a00, a11 = a00;
#pragma unroll 4
    for (int k0 = 0; k0 < 512; k0 += 32) {
        bf16x8 fa0 = *(const bf16x8*)(qin + (size_t)(qb + lr) * 512 + k0 + lk);
        bf16x8 fa1 = *(const bf16x8*)(qin + (size_t)(qb + 16 + lr) * 512 + k0 + lk);
        bf16x8 fb0 = *(const bf16x8*)(Wqbf + (size_t)(db + lr) * 512 + k0 + lk);
        bf16x8 fb1 = *(const bf16x8*)(Wqbf + (size_t)(db + 16 + lr) * 512 + k0 + lk);
        a00 = __builtin_amdgcn_mfma_f32_16x16x32_bf16(fa0, fb0, a00, 0, 0, 0);
        a01 = __builtin_amdgcn_mfma_f32_16x16x32_bf16(fa0, fb1, a01, 0, 0, 0);
        a10 = __builtin_amdgcn_mfma_f32_16x16x32_bf16(fa1, fb0, a10, 0, 0, 0);
        a11 = __builtin_amdgcn_mfma_f32_16x16x32_bf16(fa1, fb1, a11, 0, 0, 0);
    }
    int ocol = l & 15;
    float b0 = bq[db + ocol], b1 = bq[db + 16 + ocol];
#pragma unroll
    for (int r = 0; r < 4; r++) {
        int row = (l >> 4) * 4 + r;
        qp_bf[(size_t)(qb + row) * 256 + db + ocol]           = f2bf(a00[r] + b0);
        qp_bf[(size_t)(qb + row) * 256 + db + 16 + ocol]      = f2bf(a01[r] + b1);
        qp_bf[(size_t)(qb + 16 + row) * 256 + db + ocol]      = f2bf(a10[r] + b0);
        qp_bf[(size_t)(qb + 16 + row) * 256 + db + 16 + ocol] = f2bf(a11[r] + b1);
    }
}

// --------------------- qk = qp_bf @ Wk  (f32 out; B from WkT so frags contiguous)
__global__ __launch_bounds__(256) void k_gqk(const ushort* __restrict__ qp_bf,
                                             const ushort* __restrict__ WkTbf,
                                             float* __restrict__ qk) {
    int w = threadIdx.x >> 6, l = threadIdx.x & 63;
    int qb = (blockIdx.x >> 2) * 64 + (w >> 1) * 32;
    int eb = (blockIdx.x & 3) * 64 + (w & 1) * 32;
    int lr = l & 15, lk = (l >> 4) * 8;
    f32x4 a00 = {0.f,0.f,0.f,0.f}, a01 = a00, a10 = a00, a11 = a00;
#pragma unroll 4
    for (int k0 = 0; k0 < 256; k0 += 32) {
        bf16x8 fa0 = *(const bf16x8*)(qp_bf + (size_t)(qb + lr) * 256 + k0 + lk);
        bf16x8 fa1 = *(const bf16x8*)(qp_bf + (size_t)(qb + 16 + lr) * 256 + k0 + lk);
        bf16x8 fb0 = *(const bf16x8*)(WkTbf + (size_t)(eb + lr) * 256 + k0 + lk);
        bf16x8 fb1 = *(const bf16x8*)(WkTbf + (size_t)(eb + 16 + lr) * 256 + k0 + lk);
        a00 = __builtin_amdgcn_mfma_f32_16x16x32_bf16(fa0, fb0, a00, 0, 0, 0);
        a01 = __builtin_amdgcn_mfma_f32_16x16x32_bf16(fa0, fb1, a01, 0, 0, 0);
        a10 = __builtin_amdgcn_mfma_f32_16x16x32_bf16(fa1, fb0, a10, 0, 0, 0);
        a11 = __builtin_amdgcn_mfma_f32_16x16x32_bf16(fa1, fb1, a11, 0, 0, 0);
    }
    int ocol = l & 15;
#pragma unroll
    for (int r = 0; r < 4; r++) {
        int row = (l >> 4) * 4 + r;
        qk[(size_t)(qb + row) * 256 + eb + ocol]           = a00[r];
        qk[(size_t)(qb + row) * 256 + eb + 16 + ocol]      = a01[r];
        qk[(size_t)(qb + 16 + row) * 256 + eb + ocol]      = a10[r];
        qk[(size_t)(qb + 16 + row) * 256 + eb + 16 + ocol] = a11[r];
    }
}

// -------------------- h transpose: hT4[row][j4][l] = (float4)h[row][l][4j4..4j4+3]
__global__ __launch_bounds__(256) void k_htr(const float* __restrict__ h,
                                             float4* __restrict__ hT4) {
    __shared__ float hsT[256][65];   // [d][l], pad 65 -> conflict-free reads
    int row = blockIdx.x;
    int t = threadIdx.x;
    const float4* h4 = (const float4*)(h + (size_t)row * 64 * 256);
    for (int i = t; i < 4096; i += 256) {          // coalesced global read
        int l = i >> 6, d4 = i & 63;
        float4 v = h4[i];
        hsT[d4 * 4 + 0][l] = v.x; hsT[d4 * 4 + 1][l] = v.y;
        hsT[d4 * 4 + 2][l] = v.z; hsT[d4 * 4 + 3][l] = v.w;
    }
    __syncthreads();
    float4* o4 = hT4 + (size_t)row * 4096;
    for (int i = t; i < 4096; i += 256) {          // coalesced global write
        int j4 = i >> 6, l = i & 63;
        float4 o = { hsT[4 * j4 + 0][l], hsT[4 * j4 + 1][l],
                     hsT[4 * j4 + 2][l], hsT[4 * j4 + 3][l] };
        o4[i] = o;
    }
}

// ------------------------------------ attention: wave per query, coalesced h
// writes attn in bf16 (consumed only by the MFMA logit kernel)
__global__ __launch_bounds__(256) void k_attn4(const float4* __restrict__ hT4,
                                               const float* __restrict__ qk,
                                               const float* __restrict__ xsum,
                                               const int* __restrict__ pos2grp,
                                               const int* __restrict__ msk,
                                               const int* __restrict__ idx,
                                               ushort* __restrict__ attn_bf) {
    int wid  = threadIdx.x >> 6;
    int lane = threadIdx.x & 63;
    int bid = ((blockIdx.x & 7) << 8) | (blockIdx.x >> 3);   // XCD chunked swizzle
    int q = bid * 4 + wid;
    int row = idx[q];

    const float4* hT  = hT4 + (size_t)row * 4096;            // [j4][l]
    const float4* qk4 = (const float4*)(qk + (size_t)q * 256);  // wave-uniform
    float p = 0.f;
#pragma unroll 8
    for (int j4 = 0; j4 < 64; j4++) {
        float4 hv = hT[j4 * 64 + lane];                      // coalesced 1KB
        float4 qv = qk4[j4];
        p = fmaf(hv.x, qv.x, fmaf(hv.y, qv.y,
            fmaf(hv.z, qv.z, fmaf(hv.w, qv.w, p))));
    }
    int v = msk[row * 64 + lane];
    float s = v ? p * 0.0625f : -INFINITY;

    float m = s;
#pragma unroll
    for (int off = 32; off; off >>= 1) m = fmaxf(m, __shfl_xor(m, off));
    float e = expf(s - m);
    float sum = e;
#pragma unroll
    for (int off = 32; off; off >>= 1) sum += __shfl_xor(sum, off);
    float a = e / sum;

    int g_l = pos2grp[row * 64 + lane];                      // coalesced once
    float acc = 0.f;
#pragma unroll 8
    for (int l = 0; l < 64; l++) {
        float al = __shfl(a, l);
        int g = __shfl(g_l, l);
        acc = fmaf(al, xsum[(size_t)g * 64 + lane], acc);    // coalesced 256B
    }
    attn_bf[(size_t)q * 64 + lane] = f2bf(acc);
}

// ----------- logit v4: bf16 MFMA. wave = 16q x 16typ tile, K=576, no LDS.
// A = [qin | attn_bf] rows (bf16, already materialized); B = Wrelbf rows.
// D layout: row=(l>>4)*4+r (query), col=l&15 (typ) -> ballot gives 16-typ
// groups in consecutive bits; metrics fall out per 16-bit group.
__global__ __launch_bounds__(256) void k_logit4(const ushort* __restrict__ qin,
                                                const ushort* __restrict__ attn_bf,
                                                const ushort* __restrict__ Wrelbf,
                                                const float* __restrict__ brel,
                                                const int* __restrict__ idx,
                                                const int* __restrict__ typ,
                                                float* __restrict__ out,
                                                int* __restrict__ em,
                                                int* __restrict__ eqcnt) {
    __shared__ int cnt;
    int w = threadIdx.x >> 6, l = threadIdx.x & 63;
    int qb = blockIdx.x * 64 + w * 16;
    int lr = l & 15, lk = (l >> 4) * 8;
    if (threadIdx.x == 0) cnt = 0;
    __syncthreads();

    f32x4 acc = {0.f, 0.f, 0.f, 0.f};
    const ushort* wrow = Wrelbf + lr * 576;
#pragma unroll 4
    for (int k0 = 0; k0 < 512; k0 += 32) {
        bf16x8 fa = *(const bf16x8*)(qin + (size_t)(qb + lr) * 512 + k0 + lk);
        bf16x8 fb = *(const bf16x8*)(wrow + k0 + lk);
        acc = __builtin_amdgcn_mfma_f32_16x16x32_bf16(fa, fb, acc, 0, 0, 0);
    }
#pragma unroll
    for (int k0 = 0; k0 < 64; k0 += 32) {
        bf16x8 fa = *(const bf16x8*)(attn_bf + (size_t)(qb + lr) * 64 + k0 + lk);
        bf16x8 fb = *(const bf16x8*)(wrow + 512 + k0 + lk);
        acc = __builtin_amdgcn_mfma_f32_16x16x32_bf16(fa, fb, acc, 0, 0, 0);
    }

    float b = brel[lr];
    int localcnt = 0;
#pragma unroll
    for (int r = 0; r < 4; r++) {
        int q = qb + (l >> 4) * 4 + r;
        float val = acc[r] + b;
        out[(size_t)q * 16 + lr] = val;
        int eq = ((val > 0.f) == (typ[q * 16 + lr] > 0)) ? 1 : 0;
        unsigned long long mask = __ballot(eq);
        if (lr == 0) {                       // lane l = qg*16 handles its query
            unsigned bits = (unsigned)((mask >> ((l >> 4) * 16)) & 0xFFFFull);
            localcnt += __popc(bits);
            int all = (bits == 0xFFFFu) ? 1 : 0;
            atomicMin(&em[idx[q]], all);
        }
    }
    if (lr == 0) atomicAdd(&cnt, localcnt);
    __syncthreads();
    if (threadIdx.x == 0) atomicAdd(eqcnt, cnt);
}

// ---------------------------------------------------------------- finalize
__global__ void k_fin(const int* __restrict__ em, const int* __restrict__ eqcnt,
                      float* __restrict__ out) {
    __shared__ float ssum[512];
    int t = threadIdx.x;
    int v = em[t];
    out[131074 + t] = (float)v;
    ssum[t] = (float)v;
    __syncthreads();
    for (int s = 256; s; s >>= 1) {
        if (t < s) ssum[t] += ssum[t + s];
        __syncthreads();
    }
    if (t == 0) {
        out[131073] = ssum[0] / 512.0f;
        out[131072] = (float)(*eqcnt) / (float)(Q_ * NTYP);
    }
}

extern "C" void kernel_launch(void* const* d_in, const int* in_sizes, int n_in,
                              void* d_out, int out_size, void* d_ws, size_t ws_size,
                              hipStream_t stream) {
    const float* h    = (const float*)d_in[0];
    const float* tok  = (const float*)d_in[1];
    const float* Wq   = (const float*)d_in[2];
    const float* bq   = (const float*)d_in[3];
    const float* Wk   = (const float*)d_in[4];
    const float* Wrel = (const float*)d_in[6];
    const float* brel = (const float*)d_in[7];
    const int* mem     = (const int*)d_in[8];
    const int* grp     = (const int*)d_in[9];
    const int* pos2grp = (const int*)d_in[10];
    const int* msk     = (const int*)d_in[11];
    const int* idx     = (const int*)d_in[12];
    const int* src     = (const int*)d_in[13];
    const int* dst     = (const int*)d_in[14];
    const int* typ     = (const int*)d_in[15];
    float* out = (float*)d_out;

    char* ws = (char*)d_ws;
    float* xsum    = (float*)ws;                           // 0..8 MB
    float* qk      = (float*)(ws + (size_t)( 8 << 20));    // 8..16 MB
    ushort* qin    = (ushort*)(ws + (size_t)(16 << 20));   // 16..24 MB (bf16, persists to logit4)
    ushort* qp_bf  = (ushort*)(ws + (size_t)(24 << 20));   // 24..28 MB (dead after k_gqk)
    ushort* attn_bf= (ushort*)(ws + (size_t)(24 << 20));   // reuse qp_bf region (1 MB)
    float4* hT4    = (float4*)(ws + (size_t)(28 << 20));   // 28..60 MB
    int* counts     = (int*)(ws + (size_t)(60 << 20));               // 128 KB
    int* offsets    = (int*)(ws + (size_t)(60 << 20) + (128 << 10)); // 128 KB
    int* cursor     = (int*)(ws + (size_t)(60 << 20) + (256 << 10)); // 128 KB
    int* sorted_mem = (int*)(ws + (size_t)(60 << 20) + (384 << 10)); // 1 MB
    int* em         = (int*)(ws + (size_t)(61 << 20) + (512 << 10)); // 2 KB
    int* eqcnt      = (int*)(ws + (size_t)(61 << 20) + (516 << 10));
    ushort* Wqbf    = (ushort*)(ws + (size_t)(61 << 20) + (520 << 10)); // 256 KB
    ushort* WkTbf   = (ushort*)(ws + (size_t)(61 << 20) + (776 << 10)); // 128 KB
    ushort* Wrelbf  = (ushort*)(ws + (size_t)(61 << 20) + (904 << 10)); // 18 KB

    k_init<<<1, 512, 0, stream>>>(em, eqcnt);
    hipMemsetAsync(counts, 0, (size_t)NSEG * 4, stream);
    k_hist<<<NMEM / 256, 256, 0, stream>>>(grp, counts);
    k_scan<<<1, 1024, 0, stream>>>(counts, offsets, cursor);
    k_bucket<<<NMEM / 256, 256, 0, stream>>>(grp, mem, cursor, sorted_mem);
    k_gsum<<<NSEG / 4, 256, 0, stream>>>(tok, sorted_mem, offsets, counts, xsum);
    k_wcvt<<<512, 256, 0, stream>>>(Wq, Wk, Wrel, Wqbf, WkTbf, Wrelbf);
    k_qin<<<Q_ / 2, 256, 0, stream>>>(h, idx, src, dst, qin);
    k_gqp<<<(Q_ / 64) * 4, 256, 0, stream>>>(qin, Wqbf, bq, qp_bf);
    k_gqk<<<(Q_ / 64) * 4, 256, 0, stream>>>(qp_bf, WkTbf, qk);
    k_htr<<<N_, 256, 0, stream>>>(h, hT4);
    k_attn4<<<Q_ / 4, 256, 0, stream>>>(hT4, qk, xsum, pos2grp, msk, idx, attn_bf);
    k_logit4<<<Q_ / 64, 256, 0, stream>>>(qin, attn_bf, Wrelbf, brel, idx, typ, out, em, eqcnt);
    k_fin<<<1, 512, 0, stream>>>(em, eqcnt, out);
}

// Round 14
// 238.966 us; speedup vs baseline: 1.4561x; 1.1487x over previous
//
#include <hip/hip_runtime.h>
#include <math.h>

#define N_    512
#define L_    64
#define DH    256
#define DX    64
#define Q_    8192
#define NTYP  16
#define NMEM  262144
#define NSEG  32768

typedef short bf16x8 __attribute__((ext_vector_type(8)));
typedef float f32x4  __attribute__((ext_vector_type(4)));

__device__ inline ushort f2bf(float x) {            // f32 -> bf16 RNE
    unsigned u = __float_as_uint(x);
    unsigned r = u + 0x7FFFu + ((u >> 16) & 1u);
    return (ushort)(r >> 16);
}

// ---------------------------------------------------------------- init
__global__ void k_init(int* __restrict__ em, int* __restrict__ eqcnt) {
    int t = blockIdx.x * blockDim.x + threadIdx.x;
    if (t < N_) em[t] = 0x7fffffff;   // segment_min identity (int32 max)
    if (t == 0) *eqcnt = 0;
}

// ======================= segment-sum via counting sort (no f32 atomics) ====
__global__ __launch_bounds__(256) void k_hist(const int* __restrict__ grp,
                                              int* __restrict__ counts) {
    int e = blockIdx.x * 256 + threadIdx.x;
    atomicAdd(&counts[grp[e]], 1);
}

__global__ __launch_bounds__(1024) void k_scan(const int* __restrict__ counts,
                                               int* __restrict__ offsets,
                                               int* __restrict__ cursor) {
    __shared__ int ls[1024];
    int t = threadIdx.x;
    int c[32];
    int base = t * 32;
    int s = 0;
#pragma unroll
    for (int i = 0; i < 32; i++) { c[i] = counts[base + i]; s += c[i]; }
    ls[t] = s;
    __syncthreads();
    for (int off = 1; off < 1024; off <<= 1) {   // Hillis-Steele inclusive
        int v = (t >= off) ? ls[t - off] : 0;
        __syncthreads();
        ls[t] += v;
        __syncthreads();
    }
    int excl = (t == 0) ? 0 : ls[t - 1];
#pragma unroll
    for (int i = 0; i < 32; i++) {
        offsets[base + i] = excl;
        cursor[base + i] = excl;
        excl += c[i];
    }
}

__global__ __launch_bounds__(256) void k_bucket(const int* __restrict__ grp,
                                                const int* __restrict__ mem,
                                                int* __restrict__ cursor,
                                                int* __restrict__ sorted_mem) {
    int e = blockIdx.x * 256 + threadIdx.x;
    int g = grp[e];
    int pos = atomicAdd(&cursor[g], 1);
    sorted_mem[pos] = mem[e];
}

__global__ __launch_bounds__(256) void k_gsum(const float* __restrict__ tok,
                                              const int* __restrict__ sorted_mem,
                                              const int* __restrict__ offsets,
                                              const int* __restrict__ counts,
                                              float* __restrict__ xsum) {
    int g = blockIdx.x * 4 + (threadIdx.x >> 6);
    int lane = threadIdx.x & 63;
    int beg = offsets[g], cnt = counts[g];
    float acc = 0.f;
    for (int j = 0; j < cnt; j++) {
        int m = sorted_mem[beg + j];              // wave-uniform -> scalar
        acc += tok[(size_t)m * 64 + lane];        // coalesced 256B gather
    }
    xsum[(size_t)g * 64 + lane] = acc;
}

// ------ weight conversion: Wq -> bf16, Wk -> bf16 transposed, Wrel -> bf16
__global__ __launch_bounds__(256) void k_wcvt(const float* __restrict__ Wq,
                                              const float* __restrict__ Wk,
                                              const float* __restrict__ Wrel,
                                              ushort* __restrict__ Wqbf,
                                              ushort* __restrict__ WkTbf,
                                              ushort* __restrict__ Wrelbf) {
    int i = blockIdx.x * 256 + threadIdx.x;       // grid 512 blocks
    if (i < 131072) Wqbf[i] = f2bf(Wq[i]);        // [d][k], k=512
    if (i < 65536) {
        int kk = i >> 8, e = i & 255;
        WkTbf[e * 256 + kk] = f2bf(Wk[i]);        // [e][k]
    }
    if (i < 9216) Wrelbf[i] = f2bf(Wrel[i]);      // [typ][k], k=576
}

// --------------------- q_in gather -> bf16: qin[q][0..255]=h[r,src], [256..511]=h[r,dst]
__global__ __launch_bounds__(256) void k_qin(const float* __restrict__ h,
                                             const int* __restrict__ idx,
                                             const int* __restrict__ src,
                                             const int* __restrict__ dst,
                                             ushort* __restrict__ qin) {
    int q = blockIdx.x * 2 + (threadIdx.x >> 7);
    int t = threadIdx.x & 127;                    // 128 thr/query, float4 each
    int r = idx[q];
    int pos = (t < 64) ? src[q] : dst[q];
    float4 v = *(const float4*)(h + ((size_t)r * 64 + pos) * 256 + (t & 63) * 4);
    ushort4 o = { f2bf(v.x), f2bf(v.y), f2bf(v.z), f2bf(v.w) };
    *(ushort4*)(qin + (size_t)q * 512 + t * 4) = o;
}

// --------------------- qp_bf = qin @ Wq^T + bq   (bf16 MFMA, f32 acc)
// frag layouts (HW-verified m89): A row=l&15,k=(l>>4)*8+j; B col=l&15; D row=(l>>4)*4+r,col=l&15
__global__ __launch_bounds__(256) void k_gqp(const ushort* __restrict__ qin,
                                             const ushort* __restrict__ Wqbf,
                                             const float* __restrict__ bq,
                                             ushort* __restrict__ qp_bf) {
    int w = threadIdx.x >> 6, l = threadIdx.x & 63;
    int qb = (blockIdx.x >> 2) * 64 + (w >> 1) * 32;
    int db = (blockIdx.x & 3) * 64 + (w & 1) * 32;
    int lr = l & 15, lk = (l >> 4) * 8;
    f32x4 a00 = {0.f,0.f,0.f,0.f}, a01 = a00, a10 = a00, a11 = a00;
#pragma unroll 4
    for (int k0 = 0; k0 < 512; k0 += 32) {
        bf16x8 fa0 = *(const bf16x8*)(qin + (size_t)(qb + lr) * 512 + k0 + lk);
        bf16x8 fa1 = *(const bf16x8*)(qin + (size_t)(qb + 16 + lr) * 512 + k0 + lk);
        bf16x8 fb0 = *(const bf16x8*)(Wqbf + (size_t)(db + lr) * 512 + k0 + lk);
        bf16x8 fb1 = *(const bf16x8*)(Wqbf + (size_t)(db + 16 + lr) * 512 + k0 + lk);
        a00 = __builtin_amdgcn_mfma_f32_16x16x32_bf16(fa0, fb0, a00, 0, 0, 0);
        a01 = __builtin_amdgcn_mfma_f32_16x16x32_bf16(fa0, fb1, a01, 0, 0, 0);
        a10 = __builtin_amdgcn_mfma_f32_16x16x32_bf16(fa1, fb0, a10, 0, 0, 0);
        a11 = __builtin_amdgcn_mfma_f32_16x16x32_bf16(fa1, fb1, a11, 0, 0, 0);
    }
    int ocol = l & 15;
    float b0 = bq[db + ocol], b1 = bq[db + 16 + ocol];
#pragma unroll
    for (int r = 0; r < 4; r++) {
        int row = (l >> 4) * 4 + r;
        qp_bf[(size_t)(qb + row) * 256 + db + ocol]           = f2bf(a00[r] + b0);
        qp_bf[(size_t)(qb + row) * 256 + db + 16 + ocol]      = f2bf(a01[r] + b1);
        qp_bf[(size_t)(qb + 16 + row) * 256 + db + ocol]      = f2bf(a10[r] + b0);
        qp_bf[(size_t)(qb + 16 + row) * 256 + db + 16 + ocol] = f2bf(a11[r] + b1);
    }
}

// --------------------- qk_bf = qp_bf @ Wk  (bf16 out; consumed by MFMA attn)
__global__ __launch_bounds__(256) void k_gqk(const ushort* __restrict__ qp_bf,
                                             const ushort* __restrict__ WkTbf,
                                             ushort* __restrict__ qk_bf) {
    int w = threadIdx.x >> 6, l = threadIdx.x & 63;
    int qb = (blockIdx.x >> 2) * 64 + (w >> 1) * 32;
    int eb = (blockIdx.x & 3) * 64 + (w & 1) * 32;
    int lr = l & 15, lk = (l >> 4) * 8;
    f32x4 a00 = {0.f,0.f,0.f,0.f}, a01 = a00, a10 = a00, a11 = a00;
#pragma unroll 4
    for (int k0 = 0; k0 < 256; k0 += 32) {
        bf16x8 fa0 = *(const bf16x8*)(qp_bf + (size_t)(qb + lr) * 256 + k0 + lk);
        bf16x8 fa1 = *(const bf16x8*)(qp_bf + (size_t)(qb + 16 + lr) * 256 + k0 + lk);
        bf16x8 fb0 = *(const bf16x8*)(WkTbf + (size_t)(eb + lr) * 256 + k0 + lk);
        bf16x8 fb1 = *(const bf16x8*)(WkTbf + (size_t)(eb + 16 + lr) * 256 + k0 + lk);
        a00 = __builtin_amdgcn_mfma_f32_16x16x32_bf16(fa0, fb0, a00, 0, 0, 0);
        a01 = __builtin_amdgcn_mfma_f32_16x16x32_bf16(fa0, fb1, a01, 0, 0, 0);
        a10 = __builtin_amdgcn_mfma_f32_16x16x32_bf16(fa1, fb0, a10, 0, 0, 0);
        a11 = __builtin_amdgcn_mfma_f32_16x16x32_bf16(fa1, fb1, a11, 0, 0, 0);
    }
    int ocol = l & 15;
#pragma unroll
    for (int r = 0; r < 4; r++) {
        int row = (l >> 4) * 4 + r;
        qk_bf[(size_t)(qb + row) * 256 + eb + ocol]           = f2bf(a00[r]);
        qk_bf[(size_t)(qb + row) * 256 + eb + 16 + ocol]      = f2bf(a01[r]);
        qk_bf[(size_t)(qb + 16 + row) * 256 + eb + ocol]      = f2bf(a10[r]);
        qk_bf[(size_t)(qb + 16 + row) * 256 + eb + 16 + ocol] = f2bf(a11[r]);
    }
}

// =========== attention v5: one block per h-row, all-MFMA =================
// Stage h row (bf16) + xsum^T (bf16) once in LDS; each wave takes a 16-query
// chunk: S = qk_bf(16x256) @ hrow^T -> in-reg softmax -> P via LDS -> PV MFMA.
__global__ __launch_bounds__(256) void k_attn5(const float* __restrict__ h,
                                               const ushort* __restrict__ qk_bf,
                                               const float* __restrict__ xsum,
                                               const int* __restrict__ pos2grp,
                                               const int* __restrict__ msk,
                                               const int* __restrict__ idx,
                                               ushort* __restrict__ attn_bf) {
    __shared__ ushort hs[64][264];     // h row bf16 [l][d], pad 264 (2-way max)
    __shared__ ushort xgT[64][72];     // xsum^T bf16 [d][pos], pad 72
    __shared__ float  svalid[64];      // 0 or -inf per position
    __shared__ ushort pa[4][16][72];   // per-wave P bf16 [q][pos]

    int row = blockIdx.x;
    int lo = 0, hi = Q_;
    while (lo < hi) { int mid = (lo + hi) >> 1; if (idx[mid] < row) lo = mid + 1; else hi = mid; }
    int qlo = lo;
    hi = Q_;
    while (lo < hi) { int mid = (lo + hi) >> 1; if (idx[mid] <= row) lo = mid + 1; else hi = mid; }
    int qhi = lo;
    if (qlo == qhi) return;

    int t = threadIdx.x;
    {   // h row -> bf16 LDS (coalesced read, contiguous LDS write)
        const float4* h4 = (const float4*)(h + (size_t)row * 16384);
        for (int i = t; i < 4096; i += 256) {
            int l = i >> 6, d4 = i & 63;
            float4 v = h4[i];
            ushort4 o = { f2bf(v.x), f2bf(v.y), f2bf(v.z), f2bf(v.w) };
            *(ushort4*)(&hs[l][d4 * 4]) = o;
        }
    }
    {   // xsum gather -> transposed bf16 LDS
        int pos = t & 63, part = t >> 6;
        int g = pos2grp[row * 64 + pos];
#pragma unroll
        for (int m = 0; m < 4; m++) {
            float4 v = *(const float4*)(xsum + (size_t)g * 64 + part * 16 + m * 4);
            int d = part * 16 + m * 4;
            xgT[d + 0][pos] = f2bf(v.x);
            xgT[d + 1][pos] = f2bf(v.y);
            xgT[d + 2][pos] = f2bf(v.z);
            xgT[d + 3][pos] = f2bf(v.w);
        }
    }
    if (t < 64) svalid[t] = msk[row * 64 + t] ? 0.f : -INFINITY;
    __syncthreads();

    int w = t >> 6, l = t & 63;
    int lr = l & 15, lk = (l >> 4) * 8;

    for (int c0 = qlo + w * 16; c0 < qhi; c0 += 64) {
        int qa = c0 + lr; if (qa >= qhi) qa = qhi - 1;   // clamp-pad A rows

        // S = qk_bf rows @ hrow^T : 4 position-tiles x 8 k-steps
        f32x4 sacc[4];
        sacc[0] = (f32x4){0.f,0.f,0.f,0.f}; sacc[1] = sacc[0];
        sacc[2] = sacc[0]; sacc[3] = sacc[0];
#pragma unroll
        for (int k0 = 0; k0 < 256; k0 += 32) {
            bf16x8 fa = *(const bf16x8*)(qk_bf + (size_t)qa * 256 + k0 + lk);
            bf16x8 fb0 = *(const bf16x8*)(&hs[ 0 + lr][k0 + lk]);
            bf16x8 fb1 = *(const bf16x8*)(&hs[16 + lr][k0 + lk]);
            bf16x8 fb2 = *(const bf16x8*)(&hs[32 + lr][k0 + lk]);
            bf16x8 fb3 = *(const bf16x8*)(&hs[48 + lr][k0 + lk]);
            sacc[0] = __builtin_amdgcn_mfma_f32_16x16x32_bf16(fa, fb0, sacc[0], 0, 0, 0);
            sacc[1] = __builtin_amdgcn_mfma_f32_16x16x32_bf16(fa, fb1, sacc[1], 0, 0, 0);
            sacc[2] = __builtin_amdgcn_mfma_f32_16x16x32_bf16(fa, fb2, sacc[2], 0, 0, 0);
            sacc[3] = __builtin_amdgcn_mfma_f32_16x16x32_bf16(fa, fb3, sacc[3], 0, 0, 0);
        }

        // mask + scale; softmax per q-row (rows live in 16-lane groups)
        float s[4][4];
#pragma unroll
        for (int pt = 0; pt < 4; pt++) {
            float vmask = svalid[pt * 16 + lr];
#pragma unroll
            for (int r = 0; r < 4; r++) s[pt][r] = sacc[pt][r] * 0.0625f + vmask;
        }
#pragma unroll
        for (int r = 0; r < 4; r++) {
            float m = fmaxf(fmaxf(s[0][r], s[1][r]), fmaxf(s[2][r], s[3][r]));
            m = fmaxf(m, __shfl_xor(m, 1));
            m = fmaxf(m, __shfl_xor(m, 2));
            m = fmaxf(m, __shfl_xor(m, 4));
            m = fmaxf(m, __shfl_xor(m, 8));
#pragma unroll
            for (int pt = 0; pt < 4; pt++) s[pt][r] = expf(s[pt][r] - m);
            float ss = ((s[0][r] + s[1][r]) + (s[2][r] + s[3][r]));
            ss += __shfl_xor(ss, 1);
            ss += __shfl_xor(ss, 2);
            ss += __shfl_xor(ss, 4);
            ss += __shfl_xor(ss, 8);
            float inv = 1.f / ss;
#pragma unroll
            for (int pt = 0; pt < 4; pt++) s[pt][r] *= inv;
        }

        // P -> wave-private LDS (transpose to A-frag layout)
#pragma unroll
        for (int pt = 0; pt < 4; pt++)
#pragma unroll
            for (int r = 0; r < 4; r++)
                pa[w][(l >> 4) * 4 + r][pt * 16 + lr] = f2bf(s[pt][r]);

        // PV: attn(16xq,64d) = P(16x64) @ xgT rows : 4 d-tiles x 2 k-steps
        f32x4 oacc[4];
        oacc[0] = (f32x4){0.f,0.f,0.f,0.f}; oacc[1] = oacc[0];
        oacc[2] = oacc[0]; oacc[3] = oacc[0];
#pragma unroll
        for (int k0 = 0; k0 < 64; k0 += 32) {
            bf16x8 fa2 = *(const bf16x8*)(&pa[w][lr][k0 + lk]);
            bf16x8 fb0 = *(const bf16x8*)(&xgT[ 0 + lr][k0 + lk]);
            bf16x8 fb1 = *(const bf16x8*)(&xgT[16 + lr][k0 + lk]);
            bf16x8 fb2 = *(const bf16x8*)(&xgT[32 + lr][k0 + lk]);
            bf16x8 fb3 = *(const bf16x8*)(&xgT[48 + lr][k0 + lk]);
            oacc[0] = __builtin_amdgcn_mfma_f32_16x16x32_bf16(fa2, fb0, oacc[0], 0, 0, 0);
            oacc[1] = __builtin_amdgcn_mfma_f32_16x16x32_bf16(fa2, fb1, oacc[1], 0, 0, 0);
            oacc[2] = __builtin_amdgcn_mfma_f32_16x16x32_bf16(fa2, fb2, oacc[2], 0, 0, 0);
            oacc[3] = __builtin_amdgcn_mfma_f32_16x16x32_bf16(fa2, fb3, oacc[3], 0, 0, 0);
        }
#pragma unroll
        for (int r = 0; r < 4; r++) {
            int q = c0 + (l >> 4) * 4 + r;
            if (q < qhi) {
#pragma unroll
                for (int dt = 0; dt < 4; dt++)
                    attn_bf[(size_t)q * 64 + dt * 16 + lr] = f2bf(oacc[dt][r]);
            }
        }
    }
}

// ----------- logit v4: bf16 MFMA. wave = 16q x 16typ tile, K=576, no LDS.
__global__ __launch_bounds__(256) void k_logit4(const ushort* __restrict__ qin,
                                                const ushort* __restrict__ attn_bf,
                                                const ushort* __restrict__ Wrelbf,
                                                const float* __restrict__ brel,
                                                const int* __restrict__ idx,
                                                const int* __restrict__ typ,
                                                float* __restrict__ out,
                                                int* __restrict__ em,
                                                int* __restrict__ eqcnt) {
    __shared__ int cnt;
    int w = threadIdx.x >> 6, l = threadIdx.x & 63;
    int qb = blockIdx.x * 64 + w * 16;
    int lr = l & 15, lk = (l >> 4) * 8;
    if (threadIdx.x == 0) cnt = 0;
    __syncthreads();

    f32x4 acc = {0.f, 0.f, 0.f, 0.f};
    const ushort* wrow = Wrelbf + lr * 576;
#pragma unroll 4
    for (int k0 = 0; k0 < 512; k0 += 32) {
        bf16x8 fa = *(const bf16x8*)(qin + (size_t)(qb + lr) * 512 + k0 + lk);
        bf16x8 fb = *(const bf16x8*)(wrow + k0 + lk);
        acc = __builtin_amdgcn_mfma_f32_16x16x32_bf16(fa, fb, acc, 0, 0, 0);
    }
#pragma unroll
    for (int k0 = 0; k0 < 64; k0 += 32) {
        bf16x8 fa = *(const bf16x8*)(attn_bf + (size_t)(qb + lr) * 64 + k0 + lk);
        bf16x8 fb = *(const bf16x8*)(wrow + 512 + k0 + lk);
        acc = __builtin_amdgcn_mfma_f32_16x16x32_bf16(fa, fb, acc, 0, 0, 0);
    }

    float b = brel[lr];
    int localcnt = 0;
#pragma unroll
    for (int r = 0; r < 4; r++) {
        int q = qb + (l >> 4) * 4 + r;
        float val = acc[r] + b;
        out[(size_t)q * 16 + lr] = val;
        int eq = ((val > 0.f) == (typ[q * 16 + lr] > 0)) ? 1 : 0;
        unsigned long long mask = __ballot(eq);
        if (lr == 0) {                       // lane l = qg*16 handles its query
            unsigned bits = (unsigned)((mask >> ((l >> 4) * 16)) & 0xFFFFull);
            localcnt += __popc(bits);
            int all = (bits == 0xFFFFu) ? 1 : 0;
            atomicMin(&em[idx[q]], all);
        }
    }
    if (lr == 0) atomicAdd(&cnt, localcnt);
    __syncthreads();
    if (threadIdx.x == 0) atomicAdd(eqcnt, cnt);
}

// ---------------------------------------------------------------- finalize
__global__ void k_fin(const int* __restrict__ em, const int* __restrict__ eqcnt,
                      float* __restrict__ out) {
    __shared__ float ssum[512];
    int t = threadIdx.x;
    int v = em[t];
    out[131074 + t] = (float)v;
    ssum[t] = (float)v;
    __syncthreads();
    for (int s = 256; s; s >>= 1) {
        if (t < s) ssum[t] += ssum[t + s];
        __syncthreads();
    }
    if (t == 0) {
        out[131073] = ssum[0] / 512.0f;
        out[131072] = (float)(*eqcnt) / (float)(Q_ * NTYP);
    }
}

extern "C" void kernel_launch(void* const* d_in, const int* in_sizes, int n_in,
                              void* d_out, int out_size, void* d_ws, size_t ws_size,
                              hipStream_t stream) {
    const float* h    = (const float*)d_in[0];
    const float* tok  = (const float*)d_in[1];
    const float* Wq   = (const float*)d_in[2];
    const float* bq   = (const float*)d_in[3];
    const float* Wk   = (const float*)d_in[4];
    const float* Wrel = (const float*)d_in[6];
    const float* brel = (const float*)d_in[7];
    const int* mem     = (const int*)d_in[8];
    const int* grp     = (const int*)d_in[9];
    const int* pos2grp = (const int*)d_in[10];
    const int* msk     = (const int*)d_in[11];
    const int* idx     = (const int*)d_in[12];
    const int* src     = (const int*)d_in[13];
    const int* dst     = (const int*)d_in[14];
    const int* typ     = (const int*)d_in[15];
    float* out = (float*)d_out;

    char* ws = (char*)d_ws;
    float* xsum    = (float*)ws;                           // 0..8 MB
    ushort* qk_bf  = (ushort*)(ws + (size_t)( 8 << 20));   // 8..12 MB (bf16)
    ushort* qin    = (ushort*)(ws + (size_t)(16 << 20));   // 16..24 MB (bf16, persists)
    ushort* qp_bf  = (ushort*)(ws + (size_t)(24 << 20));   // 24..28 MB (dead after gqk)
    ushort* attn_bf= (ushort*)(ws + (size_t)(24 << 20));   // reuse qp_bf region (1 MB)
    int* counts     = (int*)(ws + (size_t)(60 << 20));               // 128 KB
    int* offsets    = (int*)(ws + (size_t)(60 << 20) + (128 << 10)); // 128 KB
    int* cursor     = (int*)(ws + (size_t)(60 << 20) + (256 << 10)); // 128 KB
    int* sorted_mem = (int*)(ws + (size_t)(60 << 20) + (384 << 10)); // 1 MB
    int* em         = (int*)(ws + (size_t)(61 << 20) + (512 << 10)); // 2 KB
    int* eqcnt      = (int*)(ws + (size_t)(61 << 20) + (516 << 10));
    ushort* Wqbf    = (ushort*)(ws + (size_t)(61 << 20) + (520 << 10)); // 256 KB
    ushort* WkTbf   = (ushort*)(ws + (size_t)(61 << 20) + (776 << 10)); // 128 KB
    ushort* Wrelbf  = (ushort*)(ws + (size_t)(61 << 20) + (904 << 10)); // 18 KB

    k_init<<<1, 512, 0, stream>>>(em, eqcnt);
    hipMemsetAsync(counts, 0, (size_t)NSEG * 4, stream);
    k_hist<<<NMEM / 256, 256, 0, stream>>>(grp, counts);
    k_scan<<<1, 1024, 0, stream>>>(counts, offsets, cursor);
    k_bucket<<<NMEM / 256, 256, 0, stream>>>(grp, mem, cursor, sorted_mem);
    k_gsum<<<NSEG / 4, 256, 0, stream>>>(tok, sorted_mem, offsets, counts, xsum);
    k_wcvt<<<512, 256, 0, stream>>>(Wq, Wk, Wrel, Wqbf, WkTbf, Wrelbf);
    k_qin<<<Q_ / 2, 256, 0, stream>>>(h, idx, src, dst, qin);
    k_gqp<<<(Q_ / 64) * 4, 256, 0, stream>>>(qin, Wqbf, bq, qp_bf);
    k_gqk<<<(Q_ / 64) * 4, 256, 0, stream>>>(qp_bf, WkTbf, qk_bf);
    k_attn5<<<N_, 256, 0, stream>>>(h, qk_bf, xsum, pos2grp, msk, idx, attn_bf);
    k_logit4<<<Q_ / 64, 256, 0, stream>>>(qin, attn_bf, Wrelbf, brel, idx, typ, out, em, eqcnt);
    k_fin<<<1, 512, 0, stream>>>(em, eqcnt, out);
}